// Round 2
// baseline (377.119 us; speedup 1.0000x reference)
//
#include <hip/hip_runtime.h>
#include <hip/hip_bf16.h>

// MultiHeadAttention: x(2,2048,1024) fp32 -> out(2,2048,1024) fp32
// Pipeline: cvt->bf16; QKV GEMM (mfma bf16) -> q(*0.125),k,v^T; flash attn; out GEMM.

typedef __bf16 bf16x8 __attribute__((ext_vector_type(8)));
typedef float f32x4 __attribute__((ext_vector_type(4)));

__device__ __forceinline__ unsigned short f2bf(float f) {
    union { float f; unsigned int u; } v; v.f = f;
    return (unsigned short)((v.u + 0x7FFFu + ((v.u >> 16) & 1u)) >> 16);
}

__global__ void cvt_f32_bf16_v4(const float4* __restrict__ src,
                                ushort4* __restrict__ dst, int n4) {
    int i = blockIdx.x * blockDim.x + threadIdx.x;
    int stride = gridDim.x * blockDim.x;
    for (; i < n4; i += stride) {
        float4 f = src[i];
        ushort4 o;
        o.x = f2bf(f.x); o.y = f2bf(f.y); o.z = f2bf(f.z); o.w = f2bf(f.w);
        dst[i] = o;
    }
}

// C = A(M x 1024) @ W(N x 1024)^T + bias. 128x128 block tile, 4 waves (2x2) of 64x64.
// MODE 0: N=3072, scatter to q (scaled 0.125), k, vt (v transposed [bh][dk][n]) as bf16.
// MODE 1: N=1024, fp32 out row-major.
template<int MODE>
__global__ __launch_bounds__(256) void gemm_mfma(
    const unsigned short* __restrict__ A,
    const unsigned short* __restrict__ W,
    const float* __restrict__ bias,
    unsigned short* __restrict__ qo,
    unsigned short* __restrict__ ko,
    unsigned short* __restrict__ vto,
    float* __restrict__ fo) {
    const int lane = threadIdx.x & 63;
    const int wave = threadIdx.x >> 6;
    const int g = lane >> 4, c = lane & 15;
    const int wr = wave >> 1, wc = wave & 1;
    const int row0 = blockIdx.x * 128 + wr * 64;
    const int col0 = blockIdx.y * 128 + wc * 64;

    f32x4 acc[4][4] = {};
    const unsigned short* Ab = A + (size_t)(row0 + c) * 1024 + 8 * g;
    const unsigned short* Wb = W + (size_t)(col0 + c) * 1024 + 8 * g;

    for (int kk = 0; kk < 1024; kk += 32) {
        bf16x8 a[4], b[4];
        #pragma unroll
        for (int mi = 0; mi < 4; ++mi)
            a[mi] = *(const bf16x8*)(Ab + mi * 16 * 1024 + kk);
        #pragma unroll
        for (int ni = 0; ni < 4; ++ni)
            b[ni] = *(const bf16x8*)(Wb + ni * 16 * 1024 + kk);
        #pragma unroll
        for (int mi = 0; mi < 4; ++mi) {
            #pragma unroll
            for (int ni = 0; ni < 4; ++ni)
                acc[mi][ni] = __builtin_amdgcn_mfma_f32_16x16x32_bf16(
                    a[mi], b[ni], acc[mi][ni], 0, 0, 0);
        }
    }

    #pragma unroll
    for (int mi = 0; mi < 4; ++mi) {
        #pragma unroll
        for (int ni = 0; ni < 4; ++ni) {
            const int col = col0 + ni * 16 + c;
            const float bv = bias[col];
            #pragma unroll
            for (int j = 0; j < 4; ++j) {
                const int row = row0 + mi * 16 + 4 * g + j;
                float v = acc[mi][ni][j] + bv;
                if (MODE == 1) {
                    fo[(size_t)row * 1024 + col] = v;
                } else {
                    const int sec = col >> 10;          // 0=q 1=k 2=v
                    const int d = col & 1023;
                    const int h = d >> 6, dk = d & 63;
                    const int b_ = row >> 11, n = row & 2047;
                    const int bh = b_ * 16 + h;
                    if (sec == 0)
                        qo[((size_t)(bh * 2048 + n) << 6) + dk] = f2bf(v * 0.125f);
                    else if (sec == 1)
                        ko[((size_t)(bh * 2048 + n) << 6) + dk] = f2bf(v);
                    else
                        vto[(size_t)(bh * 64 + dk) * 2048 + n] = f2bf(v);
                }
            }
        }
    }
}

// Flash attention. Q,K: [32][2048][64] bf16 (Q pre-scaled). Vt: [32][64][2048] bf16.
// O: [4096][1024] bf16 (row = b*2048+n, col = h*64+dk).
// Block: 4 waves, each owns 16 q-rows; loop kv in tiles of 64.
// Pipelined: V(t) issued before softmax; K(t+1) issued before PV.
__global__ __launch_bounds__(256, 4) void attn_flash(
    const unsigned short* __restrict__ Q,
    const unsigned short* __restrict__ K,
    const unsigned short* __restrict__ Vt,
    unsigned short* __restrict__ O) {
    __shared__ __attribute__((aligned(16))) unsigned short P_lds[4][16][72];
    const int lane = threadIdx.x & 63;
    const int w = threadIdx.x >> 6;
    const int g = lane >> 4, c = lane & 15;
    const int bh = blockIdx.y;
    const int q0 = blockIdx.x * 64 + w * 16;
    const unsigned short* Qb = Q + (size_t)bh * 2048 * 64;
    const unsigned short* Kb = K + (size_t)bh * 2048 * 64;
    const unsigned short* Vb = Vt + (size_t)bh * 64 * 2048;

    bf16x8 aq[2];
    #pragma unroll
    for (int ks = 0; ks < 2; ++ks)
        aq[ks] = *(const bf16x8*)(Qb + (size_t)(q0 + c) * 64 + ks * 32 + 8 * g);

    f32x4 o[4] = {};
    float m_run[4], l_run[4];
    #pragma unroll
    for (int j = 0; j < 4; ++j) { m_run[j] = -1e30f; l_run[j] = 0.f; }

    // ones B-fragment for MFMA-based row sums
    bf16x8 onesf;
    #pragma unroll
    for (int i = 0; i < 8; ++i) onesf[i] = (__bf16)1.0f;

    bf16x8 kf[8];
    #pragma unroll
    for (int nj = 0; nj < 4; ++nj)
        #pragma unroll
        for (int ks = 0; ks < 2; ++ks)
            kf[nj * 2 + ks] = *(const bf16x8*)(Kb + (size_t)(nj * 16 + c) * 64 + ks * 32 + 8 * g);

    for (int kv = 0; kv < 2048; kv += 64) {
        // QK^T
        f32x4 s[4] = {};
        #pragma unroll
        for (int nj = 0; nj < 4; ++nj)
            #pragma unroll
            for (int ks = 0; ks < 2; ++ks)
                s[nj] = __builtin_amdgcn_mfma_f32_16x16x32_bf16(
                    aq[ks], kf[nj * 2 + ks], s[nj], 0, 0, 0);

        // issue V loads for this tile (consumed after softmax)
        bf16x8 vf[8];
        #pragma unroll
        for (int ni = 0; ni < 4; ++ni)
            #pragma unroll
            for (int ks = 0; ks < 2; ++ks)
                vf[ni * 2 + ks] = *(const bf16x8*)(Vb + (size_t)(ni * 16 + c) * 2048 + kv + ks * 32 + 8 * g);

        // online softmax; rows are 4g+j, reduce over 16 c-lanes
        float sc_[4];
        #pragma unroll
        for (int j = 0; j < 4; ++j) {
            float mx = fmaxf(fmaxf(s[0][j], s[1][j]), fmaxf(s[2][j], s[3][j]));
            #pragma unroll
            for (int msk = 1; msk <= 8; msk <<= 1)
                mx = fmaxf(mx, __shfl_xor(mx, msk));
            const float mnew = fmaxf(m_run[j], mx);
            sc_[j] = __expf(m_run[j] - mnew);
            m_run[j] = mnew;
            #pragma unroll
            for (int nj = 0; nj < 4; ++nj)
                s[nj][j] = __expf(s[nj][j] - mnew);
        }
        // P -> LDS (C/D layout)
        #pragma unroll
        for (int nj = 0; nj < 4; ++nj)
            #pragma unroll
            for (int j = 0; j < 4; ++j)
                P_lds[w][4 * g + j][nj * 16 + c] = f2bf(s[nj][j]);
        // rescale o
        #pragma unroll
        for (int ni = 0; ni < 4; ++ni)
            #pragma unroll
            for (int j = 0; j < 4; ++j)
                o[ni][j] *= sc_[j];

        // prefetch K for next tile (lands during PV)
        bf16x8 kn[8];
        if (kv + 64 < 2048) {
            #pragma unroll
            for (int nj = 0; nj < 4; ++nj)
                #pragma unroll
                for (int ks = 0; ks < 2; ++ks)
                    kn[nj * 2 + ks] = *(const bf16x8*)(Kb + (size_t)(kv + 64 + nj * 16 + c) * 64 + ks * 32 + 8 * g);
        }

        // PV + row-sum via ones-MFMA
        f32x4 lt = {};
        #pragma unroll
        for (int ks = 0; ks < 2; ++ks) {
            bf16x8 ap = *(const bf16x8*)&P_lds[w][c][ks * 32 + 8 * g];
            #pragma unroll
            for (int ni = 0; ni < 4; ++ni)
                o[ni] = __builtin_amdgcn_mfma_f32_16x16x32_bf16(ap, vf[ni * 2 + ks], o[ni], 0, 0, 0);
            lt = __builtin_amdgcn_mfma_f32_16x16x32_bf16(ap, onesf, lt, 0, 0, 0);
        }
        #pragma unroll
        for (int j = 0; j < 4; ++j)
            l_run[j] = l_run[j] * sc_[j] + lt[j];

        #pragma unroll
        for (int i = 0; i < 8; ++i) kf[i] = kn[i];
    }

    const int b_ = bh >> 4, h = bh & 15;
    #pragma unroll
    for (int ni = 0; ni < 4; ++ni) {
        #pragma unroll
        for (int j = 0; j < 4; ++j) {
            const int row = b_ * 2048 + q0 + 4 * g + j;
            const int col = h * 64 + ni * 16 + c;
            O[(size_t)row * 1024 + col] = f2bf(o[ni][j] / l_run[j]);
        }
    }
}

extern "C" void kernel_launch(void* const* d_in, const int* in_sizes, int n_in,
                              void* d_out, int out_size, void* d_ws, size_t ws_size,
                              hipStream_t stream) {
    const float* x     = (const float*)d_in[0];
    const float* qkv_w = (const float*)d_in[1];
    const float* qkv_b = (const float*)d_in[2];
    const float* out_w = (const float*)d_in[3];
    const float* out_b = (const float*)d_in[4];
    float* out = (float*)d_out;

    char* ws = (char*)d_ws;
    unsigned short* xb   = (unsigned short*)(ws);              //  8 MB (reused as attn-out)
    unsigned short* wqkv = (unsigned short*)(ws + (8u  << 20)); //  6 MB
    unsigned short* wout = (unsigned short*)(ws + (14u << 20)); //  2 MB
    unsigned short* qb   = (unsigned short*)(ws + (16u << 20)); //  8 MB
    unsigned short* kb   = (unsigned short*)(ws + (24u << 20)); //  8 MB
    unsigned short* vtb  = (unsigned short*)(ws + (32u << 20)); //  8 MB  (total 40 MB)

    cvt_f32_bf16_v4<<<2048, 256, 0, stream>>>((const float4*)x,     (ushort4*)xb,   4096 * 1024 / 4);
    cvt_f32_bf16_v4<<<2048, 256, 0, stream>>>((const float4*)qkv_w, (ushort4*)wqkv, 3072 * 1024 / 4);
    cvt_f32_bf16_v4<<<1024, 256, 0, stream>>>((const float4*)out_w, (ushort4*)wout, 1024 * 1024 / 4);

    gemm_mfma<0><<<dim3(32, 24), 256, 0, stream>>>(xb, wqkv, qkv_b, qb, kb, vtb, nullptr);

    unsigned short* ao = xb;  // xb no longer needed; reuse for attention output
    attn_flash<<<dim3(32, 32), 256, 0, stream>>>(qb, kb, vtb, ao);

    gemm_mfma<1><<<dim3(32, 8), 256, 0, stream>>>(ao, wout, out_b, nullptr, nullptr, nullptr, out);
}

// Round 3
// 232.896 us; speedup vs baseline: 1.6193x; 1.6193x over previous
//
#include <hip/hip_runtime.h>
#include <hip/hip_bf16.h>

// MultiHeadAttention: x(2,2048,1024) fp32 -> out(2,2048,1024) fp32
// Pipeline: cvt->bf16; QKV GEMM (mfma bf16) -> q(*0.125),k,v^T; flash attn (LDS-staged K/V); out GEMM.

typedef __bf16 bf16x8 __attribute__((ext_vector_type(8)));
typedef float f32x4 __attribute__((ext_vector_type(4)));

__device__ __forceinline__ unsigned short f2bf(float f) {
    union { float f; unsigned int u; } v; v.f = f;
    return (unsigned short)((v.u + 0x7FFFu + ((v.u >> 16) & 1u)) >> 16);
}

__device__ __forceinline__ void gl_lds16(const void* g, void* l) {
    __builtin_amdgcn_global_load_lds(
        (__attribute__((address_space(1))) const unsigned int*)g,
        (__attribute__((address_space(3))) unsigned int*)l, 16, 0, 0);
}

__global__ void cvt_f32_bf16_v4(const float4* __restrict__ src,
                                ushort4* __restrict__ dst, int n4) {
    int i = blockIdx.x * blockDim.x + threadIdx.x;
    int stride = gridDim.x * blockDim.x;
    for (; i < n4; i += stride) {
        float4 f = src[i];
        ushort4 o;
        o.x = f2bf(f.x); o.y = f2bf(f.y); o.z = f2bf(f.z); o.w = f2bf(f.w);
        dst[i] = o;
    }
}

// C = A(M x 1024) @ W(N x 1024)^T + bias. 128x128 block tile, 4 waves (2x2) of 64x64.
// MODE 0: N=3072, scatter to q (scaled 0.125), k, vt (v transposed [bh][dk][n]) as bf16.
// MODE 1: N=1024, fp32 out row-major.
template<int MODE>
__global__ __launch_bounds__(256) void gemm_mfma(
    const unsigned short* __restrict__ A,
    const unsigned short* __restrict__ W,
    const float* __restrict__ bias,
    unsigned short* __restrict__ qo,
    unsigned short* __restrict__ ko,
    unsigned short* __restrict__ vto,
    float* __restrict__ fo) {
    const int lane = threadIdx.x & 63;
    const int wave = threadIdx.x >> 6;
    const int g = lane >> 4, c = lane & 15;
    const int wr = wave >> 1, wc = wave & 1;
    const int row0 = blockIdx.x * 128 + wr * 64;
    const int col0 = blockIdx.y * 128 + wc * 64;

    f32x4 acc[4][4] = {};
    const unsigned short* Ab = A + (size_t)(row0 + c) * 1024 + 8 * g;
    const unsigned short* Wb = W + (size_t)(col0 + c) * 1024 + 8 * g;

    for (int kk = 0; kk < 1024; kk += 32) {
        bf16x8 a[4], b[4];
        #pragma unroll
        for (int mi = 0; mi < 4; ++mi)
            a[mi] = *(const bf16x8*)(Ab + mi * 16 * 1024 + kk);
        #pragma unroll
        for (int ni = 0; ni < 4; ++ni)
            b[ni] = *(const bf16x8*)(Wb + ni * 16 * 1024 + kk);
        #pragma unroll
        for (int mi = 0; mi < 4; ++mi) {
            #pragma unroll
            for (int ni = 0; ni < 4; ++ni)
                acc[mi][ni] = __builtin_amdgcn_mfma_f32_16x16x32_bf16(
                    a[mi], b[ni], acc[mi][ni], 0, 0, 0);
        }
    }

    #pragma unroll
    for (int mi = 0; mi < 4; ++mi) {
        #pragma unroll
        for (int ni = 0; ni < 4; ++ni) {
            const int col = col0 + ni * 16 + c;
            const float bv = bias[col];
            #pragma unroll
            for (int j = 0; j < 4; ++j) {
                const int row = row0 + mi * 16 + 4 * g + j;
                float v = acc[mi][ni][j] + bv;
                if (MODE == 1) {
                    fo[(size_t)row * 1024 + col] = v;
                } else {
                    const int sec = col >> 10;          // 0=q 1=k 2=v
                    const int d = col & 1023;
                    const int h = d >> 6, dk = d & 63;
                    const int b_ = row >> 11, n = row & 2047;
                    const int bh = b_ * 16 + h;
                    if (sec == 0)
                        qo[((size_t)(bh * 2048 + n) << 6) + dk] = f2bf(v * 0.125f);
                    else if (sec == 1)
                        ko[((size_t)(bh * 2048 + n) << 6) + dk] = f2bf(v);
                    else
                        vto[(size_t)(bh * 64 + dk) * 2048 + n] = f2bf(v);
                }
            }
        }
    }
}

// Flash attention, LDS-staged K/V shared by 4 waves.
// Q,K: [32][2048][64] bf16 (Q pre-scaled). Vt: [32][64][2048] bf16.
// O: [4096][1024] bf16 (row = b*2048+n, col = h*64+dk).
// Block: 4 waves x 16 q-rows = 64 q-rows. kv tiles of 64, double-buffered in LDS.
// LDS layout (bytes): K dbuf [0,16K), V dbuf [16K,32K), P per-wave [32K,40K).
// K/V tiles stored [64 rows][8 chunks of 16B], chunk position = data_chunk ^ (row&7)
// (global_load_lds writes linearly; the source global address is pre-swizzled).
__global__ __launch_bounds__(256, 4) void attn_flash(
    const unsigned short* __restrict__ Q,
    const unsigned short* __restrict__ K,
    const unsigned short* __restrict__ Vt,
    unsigned short* __restrict__ O) {
    __shared__ __attribute__((aligned(128))) unsigned char smem[40960];
    const int lane = threadIdx.x & 63;
    const int w = threadIdx.x >> 6;
    const int g = lane >> 4, c = lane & 15;
    const int c7 = c & 7;
    const int bh = blockIdx.y;
    const int q0 = blockIdx.x * 64 + w * 16;
    const unsigned short* Qb = Q + (size_t)bh * 2048 * 64;
    const unsigned short* Kb = K + (size_t)bh * 2048 * 64;
    const unsigned short* Vb = Vt + (size_t)bh * 64 * 2048;

    // staging geometry: 8 instrs of 1KB per tile; wave w issues instrs {2w, 2w+1}
    const int rloc = lane >> 3;                       // row within 8-row instr span
    const int csrc = ((lane & 7) ^ (rloc & 7)) * 8;   // pre-swizzled source chunk (elements)

    // swizzled read chunk offsets: ((ks*4+g) ^ (c&7)) * 16
    const int chunkKV0 = ((0 + g) ^ c7) * 16;
    const int chunkKV1 = ((4 + g) ^ c7) * 16;

    unsigned char* Pbase = smem + 32768 + w * 2048;   // per-wave P [16][64] swizzled
    const int swzPc = (c ^ (c >> 3)) & 7;             // read-side P swizzle for row=c

    bf16x8 aq[2];
    #pragma unroll
    for (int ks = 0; ks < 2; ++ks)
        aq[ks] = *(const bf16x8*)(Qb + (size_t)(q0 + c) * 64 + ks * 32 + 8 * g);

    f32x4 o[4] = {};
    float m_run[4], l_run[4];
    #pragma unroll
    for (int j = 0; j < 4; ++j) { m_run[j] = -1e30f; l_run[j] = 0.f; }

    bf16x8 onesf;
    #pragma unroll
    for (int i = 0; i < 8; ++i) onesf[i] = (__bf16)1.0f;

    // prologue: stage tile 0 into buffer 0
    #pragma unroll
    for (int tt = 0; tt < 2; ++tt) {
        const int t = 2 * w + tt;
        const int row = 8 * t + rloc;
        gl_lds16(Kb + (size_t)row * 64 + csrc, smem + t * 1024);
        gl_lds16(Vb + (size_t)row * 2048 + csrc, smem + 16384 + t * 1024);
    }
    __syncthreads();

    int cur = 0;
    for (int kv = 0; kv < 2048; kv += 64) {
        // issue next-tile staging into the other buffer (drained by syncthreads below)
        if (kv + 64 < 2048) {
            const int nb = cur ^ 1;
            #pragma unroll
            for (int tt = 0; tt < 2; ++tt) {
                const int t = 2 * w + tt;
                const int row = 8 * t + rloc;
                gl_lds16(Kb + (size_t)(kv + 64 + row) * 64 + csrc,
                         smem + nb * 8192 + t * 1024);
                gl_lds16(Vb + (size_t)row * 2048 + (kv + 64) + csrc,
                         smem + 16384 + nb * 8192 + t * 1024);
            }
        }

        const unsigned char* Kt = smem + cur * 8192;
        const unsigned char* Vtb = smem + 16384 + cur * 8192;

        // QK^T: S[q=4g+j][kv = nj*16+c]
        f32x4 s[4] = {};
        #pragma unroll
        for (int nj = 0; nj < 4; ++nj) {
            bf16x8 bk0 = *(const bf16x8*)(Kt + nj * 2048 + c * 128 + chunkKV0);
            bf16x8 bk1 = *(const bf16x8*)(Kt + nj * 2048 + c * 128 + chunkKV1);
            s[nj] = __builtin_amdgcn_mfma_f32_16x16x32_bf16(aq[0], bk0, s[nj], 0, 0, 0);
            s[nj] = __builtin_amdgcn_mfma_f32_16x16x32_bf16(aq[1], bk1, s[nj], 0, 0, 0);
        }

        // online softmax; rows 4g+j, reduce over 16 c-lanes
        float sc_[4];
        #pragma unroll
        for (int j = 0; j < 4; ++j) {
            float mx = fmaxf(fmaxf(s[0][j], s[1][j]), fmaxf(s[2][j], s[3][j]));
            #pragma unroll
            for (int msk = 1; msk <= 8; msk <<= 1)
                mx = fmaxf(mx, __shfl_xor(mx, msk));
            const float mnew = fmaxf(m_run[j], mx);
            sc_[j] = __expf(m_run[j] - mnew);
            m_run[j] = mnew;
            #pragma unroll
            for (int nj = 0; nj < 4; ++nj)
                s[nj][j] = __expf(s[nj][j] - mnew);
        }

        // P -> LDS (swizzled [16][64])
        #pragma unroll
        for (int nj = 0; nj < 4; ++nj) {
            #pragma unroll
            for (int j = 0; j < 4; ++j) {
                const int r = 4 * g + j;
                const int swr = (r ^ (r >> 3)) & 7;
                *(unsigned short*)(Pbase + r * 128 + (((2 * nj + (c >> 3)) ^ swr) * 16) + c7 * 2)
                    = f2bf(s[nj][j]);
            }
        }

        // rescale o
        #pragma unroll
        for (int ni = 0; ni < 4; ++ni)
            #pragma unroll
            for (int j = 0; j < 4; ++j)
                o[ni][j] *= sc_[j];

        // PV + row-sum via ones-MFMA
        f32x4 lt = {};
        #pragma unroll
        for (int ks = 0; ks < 2; ++ks) {
            bf16x8 ap = *(const bf16x8*)(Pbase + c * 128 + (((ks * 4 + g) ^ swzPc) * 16));
            const int ck = ks ? chunkKV1 : chunkKV0;
            #pragma unroll
            for (int ni = 0; ni < 4; ++ni) {
                bf16x8 bv = *(const bf16x8*)(Vtb + ni * 2048 + c * 128 + ck);
                o[ni] = __builtin_amdgcn_mfma_f32_16x16x32_bf16(ap, bv, o[ni], 0, 0, 0);
            }
            lt = __builtin_amdgcn_mfma_f32_16x16x32_bf16(ap, onesf, lt, 0, 0, 0);
        }
        #pragma unroll
        for (int j = 0; j < 4; ++j)
            l_run[j] = l_run[j] * sc_[j] + lt[j];

        __syncthreads();   // staged loads landed; all waves done reading cur
        cur ^= 1;
    }

    const int b_ = bh >> 4, h = bh & 15;
    #pragma unroll
    for (int ni = 0; ni < 4; ++ni) {
        #pragma unroll
        for (int j = 0; j < 4; ++j) {
            const int row = b_ * 2048 + q0 + 4 * g + j;
            const int col = h * 64 + ni * 16 + c;
            O[(size_t)row * 1024 + col] = f2bf(o[ni][j] / l_run[j]);
        }
    }
}

extern "C" void kernel_launch(void* const* d_in, const int* in_sizes, int n_in,
                              void* d_out, int out_size, void* d_ws, size_t ws_size,
                              hipStream_t stream) {
    const float* x     = (const float*)d_in[0];
    const float* qkv_w = (const float*)d_in[1];
    const float* qkv_b = (const float*)d_in[2];
    const float* out_w = (const float*)d_in[3];
    const float* out_b = (const float*)d_in[4];
    float* out = (float*)d_out;

    char* ws = (char*)d_ws;
    unsigned short* xb   = (unsigned short*)(ws);              //  8 MB (reused as attn-out)
    unsigned short* wqkv = (unsigned short*)(ws + (8u  << 20)); //  6 MB
    unsigned short* wout = (unsigned short*)(ws + (14u << 20)); //  2 MB
    unsigned short* qb   = (unsigned short*)(ws + (16u << 20)); //  8 MB
    unsigned short* kb   = (unsigned short*)(ws + (24u << 20)); //  8 MB
    unsigned short* vtb  = (unsigned short*)(ws + (32u << 20)); //  8 MB  (total 40 MB)

    cvt_f32_bf16_v4<<<2048, 256, 0, stream>>>((const float4*)x,     (ushort4*)xb,   4096 * 1024 / 4);
    cvt_f32_bf16_v4<<<2048, 256, 0, stream>>>((const float4*)qkv_w, (ushort4*)wqkv, 3072 * 1024 / 4);
    cvt_f32_bf16_v4<<<1024, 256, 0, stream>>>((const float4*)out_w, (ushort4*)wout, 1024 * 1024 / 4);

    gemm_mfma<0><<<dim3(32, 24), 256, 0, stream>>>(xb, wqkv, qkv_b, qb, kb, vtb, nullptr);

    unsigned short* ao = xb;  // xb no longer needed; reuse for attention output
    attn_flash<<<dim3(32, 32), 256, 0, stream>>>(qb, kb, vtb, ao);

    gemm_mfma<1><<<dim3(32, 8), 256, 0, stream>>>(ao, wout, out_b, nullptr, nullptr, nullptr, out);
}

// Round 4
// 155.177 us; speedup vs baseline: 2.4302x; 1.5008x over previous
//
#include <hip/hip_runtime.h>
#include <hip/hip_bf16.h>

// MultiHeadAttention: x(2,2048,1024) fp32 -> out(2,2048,1024) fp32
// Pipeline: cvt->bf16; QKV GEMM (LDS-staged mfma) -> q(*0.125),k,v^T; flash attn (LDS-staged K/V); out GEMM.

typedef __bf16 bf16x8 __attribute__((ext_vector_type(8)));
typedef float f32x4 __attribute__((ext_vector_type(4)));

__device__ __forceinline__ unsigned short f2bf(float f) {
    union { float f; unsigned int u; } v; v.f = f;
    return (unsigned short)((v.u + 0x7FFFu + ((v.u >> 16) & 1u)) >> 16);
}

__device__ __forceinline__ void gl_lds16(const void* g, void* l) {
    __builtin_amdgcn_global_load_lds(
        (__attribute__((address_space(1))) const unsigned int*)g,
        (__attribute__((address_space(3))) unsigned int*)l, 16, 0, 0);
}

__global__ void cvt_f32_bf16_v4(const float4* __restrict__ src,
                                ushort4* __restrict__ dst, int n4) {
    int i = blockIdx.x * blockDim.x + threadIdx.x;
    int stride = gridDim.x * blockDim.x;
    for (; i < n4; i += stride) {
        float4 f = src[i];
        ushort4 o;
        o.x = f2bf(f.x); o.y = f2bf(f.y); o.z = f2bf(f.z); o.w = f2bf(f.w);
        dst[i] = o;
    }
}

// C = A(M x 1024) @ W(N x 1024)^T + bias. 128x128 block tile, 4 waves (2x2) of 64x64.
// m97 structure: BK=64 single-buffer LDS, global_load_lds w16 staging, 2-barrier K-loop.
// LDS: As [0,16K) = [128 rows][8 chunks16B, pos = chunk^(row&7)]; Bs [16K,32K) same.
// MODE 0: N=3072, scatter to q (scaled 0.125), k, vt (v transposed [bh][dk][n]) as bf16.
// MODE 1: N=1024, fp32 out row-major.
template<int MODE>
__global__ __launch_bounds__(256, 3) void gemm_mfma(
    const unsigned short* __restrict__ A,
    const unsigned short* __restrict__ W,
    const float* __restrict__ bias,
    unsigned short* __restrict__ qo,
    unsigned short* __restrict__ ko,
    unsigned short* __restrict__ vto,
    float* __restrict__ fo) {
    __shared__ __attribute__((aligned(128))) unsigned char smem[32768];
    const int lane = threadIdx.x & 63;
    const int w = threadIdx.x >> 6;
    const int g = lane >> 4, c = lane & 15;
    const int wr = w >> 1, wc = w & 1;
    const int row0 = blockIdx.x * 128;
    const int col0 = blockIdx.y * 128;

    // staging geometry: instr i covers rows i*32 + w*8 .. +7 (1KB/wave/instr)
    const int rloc = lane >> 3;                      // 0..7
    const int csrc = ((lane & 7) ^ rloc) * 8;        // pre-swizzled source chunk (elements)

    f32x4 acc[4][4] = {};

    for (int kt = 0; kt < 1024; kt += 64) {
        #pragma unroll
        for (int i = 0; i < 4; ++i) {
            const int r = i * 32 + w * 8 + rloc;
            gl_lds16(A + (size_t)(row0 + r) * 1024 + kt + csrc,
                     smem + i * 4096 + w * 1024);
            gl_lds16(W + (size_t)(col0 + r) * 1024 + kt + csrc,
                     smem + 16384 + i * 4096 + w * 1024);
        }
        __syncthreads();

        #pragma unroll
        for (int ks = 0; ks < 2; ++ks) {
            bf16x8 a[4], b[4];
            #pragma unroll
            for (int mi = 0; mi < 4; ++mi) {
                const int r = wr * 64 + mi * 16 + c;
                a[mi] = *(const bf16x8*)(smem + r * 128 + (((ks * 4 + g) ^ (r & 7)) * 16));
            }
            #pragma unroll
            for (int ni = 0; ni < 4; ++ni) {
                const int r = wc * 64 + ni * 16 + c;
                b[ni] = *(const bf16x8*)(smem + 16384 + r * 128 + (((ks * 4 + g) ^ (r & 7)) * 16));
            }
            #pragma unroll
            for (int mi = 0; mi < 4; ++mi)
                #pragma unroll
                for (int ni = 0; ni < 4; ++ni)
                    acc[mi][ni] = __builtin_amdgcn_mfma_f32_16x16x32_bf16(
                        a[mi], b[ni], acc[mi][ni], 0, 0, 0);
        }
        __syncthreads();
    }

    #pragma unroll
    for (int mi = 0; mi < 4; ++mi) {
        #pragma unroll
        for (int ni = 0; ni < 4; ++ni) {
            const int col = col0 + wc * 64 + ni * 16 + c;
            const float bv = bias[col];
            #pragma unroll
            for (int j = 0; j < 4; ++j) {
                const int row = row0 + wr * 64 + mi * 16 + 4 * g + j;
                float v = acc[mi][ni][j] + bv;
                if (MODE == 1) {
                    fo[(size_t)row * 1024 + col] = v;
                } else {
                    const int sec = col >> 10;          // 0=q 1=k 2=v
                    const int d = col & 1023;
                    const int h = d >> 6, dk = d & 63;
                    const int b_ = row >> 11, n = row & 2047;
                    const int bh = b_ * 16 + h;
                    if (sec == 0)
                        qo[((size_t)(bh * 2048 + n) << 6) + dk] = f2bf(v * 0.125f);
                    else if (sec == 1)
                        ko[((size_t)(bh * 2048 + n) << 6) + dk] = f2bf(v);
                    else
                        vto[(size_t)(bh * 64 + dk) * 2048 + n] = f2bf(v);
                }
            }
        }
    }
}

// Flash attention, LDS-staged K/V shared by 4 waves.
// Q,K: [32][2048][64] bf16 (Q pre-scaled). Vt: [32][64][2048] bf16.
// O: [4096][1024] bf16 (row = b*2048+n, col = h*64+dk).
// Block: 4 waves x 16 q-rows = 64 q-rows. kv tiles of 64, double-buffered in LDS.
// LDS layout (bytes): K dbuf [0,16K), V dbuf [16K,32K), P per-wave [32K,40K).
__global__ __launch_bounds__(256, 4) void attn_flash(
    const unsigned short* __restrict__ Q,
    const unsigned short* __restrict__ K,
    const unsigned short* __restrict__ Vt,
    unsigned short* __restrict__ O) {
    __shared__ __attribute__((aligned(128))) unsigned char smem[40960];
    const int lane = threadIdx.x & 63;
    const int w = threadIdx.x >> 6;
    const int g = lane >> 4, c = lane & 15;
    const int c7 = c & 7;
    const int bh = blockIdx.y;
    const int q0 = blockIdx.x * 64 + w * 16;
    const unsigned short* Qb = Q + (size_t)bh * 2048 * 64;
    const unsigned short* Kb = K + (size_t)bh * 2048 * 64;
    const unsigned short* Vb = Vt + (size_t)bh * 64 * 2048;

    const int rloc = lane >> 3;
    const int csrc = ((lane & 7) ^ (rloc & 7)) * 8;

    const int chunkKV0 = ((0 + g) ^ c7) * 16;
    const int chunkKV1 = ((4 + g) ^ c7) * 16;

    unsigned char* Pbase = smem + 32768 + w * 2048;
    const int swzPc = (c ^ (c >> 3)) & 7;

    bf16x8 aq[2];
    #pragma unroll
    for (int ks = 0; ks < 2; ++ks)
        aq[ks] = *(const bf16x8*)(Qb + (size_t)(q0 + c) * 64 + ks * 32 + 8 * g);

    f32x4 o[4] = {};
    float m_run[4], l_run[4];
    #pragma unroll
    for (int j = 0; j < 4; ++j) { m_run[j] = -1e30f; l_run[j] = 0.f; }

    bf16x8 onesf;
    #pragma unroll
    for (int i = 0; i < 8; ++i) onesf[i] = (__bf16)1.0f;

    #pragma unroll
    for (int tt = 0; tt < 2; ++tt) {
        const int t = 2 * w + tt;
        const int row = 8 * t + rloc;
        gl_lds16(Kb + (size_t)row * 64 + csrc, smem + t * 1024);
        gl_lds16(Vb + (size_t)row * 2048 + csrc, smem + 16384 + t * 1024);
    }
    __syncthreads();

    int cur = 0;
    for (int kv = 0; kv < 2048; kv += 64) {
        if (kv + 64 < 2048) {
            const int nb = cur ^ 1;
            #pragma unroll
            for (int tt = 0; tt < 2; ++tt) {
                const int t = 2 * w + tt;
                const int row = 8 * t + rloc;
                gl_lds16(Kb + (size_t)(kv + 64 + row) * 64 + csrc,
                         smem + nb * 8192 + t * 1024);
                gl_lds16(Vb + (size_t)row * 2048 + (kv + 64) + csrc,
                         smem + 16384 + nb * 8192 + t * 1024);
            }
        }

        const unsigned char* Kt = smem + cur * 8192;
        const unsigned char* Vtb = smem + 16384 + cur * 8192;

        f32x4 s[4] = {};
        #pragma unroll
        for (int nj = 0; nj < 4; ++nj) {
            bf16x8 bk0 = *(const bf16x8*)(Kt + nj * 2048 + c * 128 + chunkKV0);
            bf16x8 bk1 = *(const bf16x8*)(Kt + nj * 2048 + c * 128 + chunkKV1);
            s[nj] = __builtin_amdgcn_mfma_f32_16x16x32_bf16(aq[0], bk0, s[nj], 0, 0, 0);
            s[nj] = __builtin_amdgcn_mfma_f32_16x16x32_bf16(aq[1], bk1, s[nj], 0, 0, 0);
        }

        float sc_[4];
        #pragma unroll
        for (int j = 0; j < 4; ++j) {
            float mx = fmaxf(fmaxf(s[0][j], s[1][j]), fmaxf(s[2][j], s[3][j]));
            #pragma unroll
            for (int msk = 1; msk <= 8; msk <<= 1)
                mx = fmaxf(mx, __shfl_xor(mx, msk));
            const float mnew = fmaxf(m_run[j], mx);
            sc_[j] = __expf(m_run[j] - mnew);
            m_run[j] = mnew;
            #pragma unroll
            for (int nj = 0; nj < 4; ++nj)
                s[nj][j] = __expf(s[nj][j] - mnew);
        }

        #pragma unroll
        for (int nj = 0; nj < 4; ++nj) {
            #pragma unroll
            for (int j = 0; j < 4; ++j) {
                const int r = 4 * g + j;
                const int swr = (r ^ (r >> 3)) & 7;
                *(unsigned short*)(Pbase + r * 128 + (((2 * nj + (c >> 3)) ^ swr) * 16) + c7 * 2)
                    = f2bf(s[nj][j]);
            }
        }

        #pragma unroll
        for (int ni = 0; ni < 4; ++ni)
            #pragma unroll
            for (int j = 0; j < 4; ++j)
                o[ni][j] *= sc_[j];

        f32x4 lt = {};
        #pragma unroll
        for (int ks = 0; ks < 2; ++ks) {
            bf16x8 ap = *(const bf16x8*)(Pbase + c * 128 + (((ks * 4 + g) ^ swzPc) * 16));
            const int ck = ks ? chunkKV1 : chunkKV0;
            #pragma unroll
            for (int ni = 0; ni < 4; ++ni) {
                bf16x8 bv = *(const bf16x8*)(Vtb + ni * 2048 + c * 128 + ck);
                o[ni] = __builtin_amdgcn_mfma_f32_16x16x32_bf16(ap, bv, o[ni], 0, 0, 0);
            }
            lt = __builtin_amdgcn_mfma_f32_16x16x32_bf16(ap, onesf, lt, 0, 0, 0);
        }
        #pragma unroll
        for (int j = 0; j < 4; ++j)
            l_run[j] = l_run[j] * sc_[j] + lt[j];

        __syncthreads();
        cur ^= 1;
    }

    const int b_ = bh >> 4, h = bh & 15;
    #pragma unroll
    for (int ni = 0; ni < 4; ++ni) {
        #pragma unroll
        for (int j = 0; j < 4; ++j) {
            const int row = b_ * 2048 + q0 + 4 * g + j;
            const int col = h * 64 + ni * 16 + c;
            O[(size_t)row * 1024 + col] = f2bf(o[ni][j] / l_run[j]);
        }
    }
}

extern "C" void kernel_launch(void* const* d_in, const int* in_sizes, int n_in,
                              void* d_out, int out_size, void* d_ws, size_t ws_size,
                              hipStream_t stream) {
    const float* x     = (const float*)d_in[0];
    const float* qkv_w = (const float*)d_in[1];
    const float* qkv_b = (const float*)d_in[2];
    const float* out_w = (const float*)d_in[3];
    const float* out_b = (const float*)d_in[4];
    float* out = (float*)d_out;

    char* ws = (char*)d_ws;
    unsigned short* xb   = (unsigned short*)(ws);              //  8 MB (reused as attn-out)
    unsigned short* wqkv = (unsigned short*)(ws + (8u  << 20)); //  6 MB
    unsigned short* wout = (unsigned short*)(ws + (14u << 20)); //  2 MB
    unsigned short* qb   = (unsigned short*)(ws + (16u << 20)); //  8 MB
    unsigned short* kb   = (unsigned short*)(ws + (24u << 20)); //  8 MB
    unsigned short* vtb  = (unsigned short*)(ws + (32u << 20)); //  8 MB  (total 40 MB)

    cvt_f32_bf16_v4<<<2048, 256, 0, stream>>>((const float4*)x,     (ushort4*)xb,   4096 * 1024 / 4);
    cvt_f32_bf16_v4<<<2048, 256, 0, stream>>>((const float4*)qkv_w, (ushort4*)wqkv, 3072 * 1024 / 4);
    cvt_f32_bf16_v4<<<1024, 256, 0, stream>>>((const float4*)out_w, (ushort4*)wout, 1024 * 1024 / 4);

    gemm_mfma<0><<<dim3(32, 24), 256, 0, stream>>>(xb, wqkv, qkv_b, qb, kb, vtb, nullptr);

    unsigned short* ao = xb;  // xb no longer needed; reuse for attention output
    attn_flash<<<dim3(32, 32), 256, 0, stream>>>(qb, kb, vtb, ao);

    gemm_mfma<1><<<dim3(32, 8), 256, 0, stream>>>(ao, wout, out_b, nullptr, nullptr, nullptr, out);
}

// Round 5
// 154.254 us; speedup vs baseline: 2.4448x; 1.0060x over previous
//
#include <hip/hip_runtime.h>
#include <hip/hip_bf16.h>

// MultiHeadAttention: x(2,2048,1024) fp32 -> out(2,2048,1024) fp32
// Pipeline: cvt->bf16; QKV GEMM (LDS-staged mfma) -> q(*0.125*log2e),k,v^T; flash attn
// (LDS-staged K/V, log2-domain softmax, defer-rescale); out GEMM.

typedef __bf16 bf16x8 __attribute__((ext_vector_type(8)));
typedef float f32x4 __attribute__((ext_vector_type(4)));

#define QSCALE 0.18033688011112042f  // 0.125 * log2(e): QK^T lands in log2 domain

__device__ __forceinline__ unsigned short bfbits(float f) {
    union { __bf16 h; unsigned short u; } cv;
    cv.h = (__bf16)f;
    return cv.u;
}

__device__ __forceinline__ void gl_lds16(const void* g, void* l) {
    __builtin_amdgcn_global_load_lds(
        (__attribute__((address_space(1))) const unsigned int*)g,
        (__attribute__((address_space(3))) unsigned int*)l, 16, 0, 0);
}

__global__ void cvt_f32_bf16_v4(const float4* __restrict__ src,
                                ushort4* __restrict__ dst, int n4) {
    int i = blockIdx.x * blockDim.x + threadIdx.x;
    int stride = gridDim.x * blockDim.x;
    for (; i < n4; i += stride) {
        float4 f = src[i];
        ushort4 o;
        o.x = bfbits(f.x); o.y = bfbits(f.y); o.z = bfbits(f.z); o.w = bfbits(f.w);
        dst[i] = o;
    }
}

// C = A(M x 1024) @ W(N x 1024)^T + bias. 128x128 block tile, 4 waves (2x2) of 64x64.
// m97 structure: BK=64 single-buffer LDS, global_load_lds w16 staging, 2-barrier K-loop.
// LDS: As [0,16K) = [128 rows][8 chunks16B, pos = chunk^(row&7)]; Bs [16K,32K) same.
// MODE 0: N=3072, scatter to q (scaled QSCALE), k, vt (v transposed [bh][dk][n]) as bf16.
// MODE 1: N=1024, fp32 out row-major.
template<int MODE>
__global__ __launch_bounds__(256, 3) void gemm_mfma(
    const unsigned short* __restrict__ A,
    const unsigned short* __restrict__ W,
    const float* __restrict__ bias,
    unsigned short* __restrict__ qo,
    unsigned short* __restrict__ ko,
    unsigned short* __restrict__ vto,
    float* __restrict__ fo) {
    __shared__ __attribute__((aligned(128))) unsigned char smem[32768];
    const int lane = threadIdx.x & 63;
    const int w = threadIdx.x >> 6;
    const int g = lane >> 4, c = lane & 15;
    const int wr = w >> 1, wc = w & 1;
    const int row0 = blockIdx.x * 128;
    const int col0 = blockIdx.y * 128;

    const int rloc = lane >> 3;                      // 0..7
    const int csrc = ((lane & 7) ^ rloc) * 8;        // pre-swizzled source chunk (elements)

    f32x4 acc[4][4] = {};

    for (int kt = 0; kt < 1024; kt += 64) {
        #pragma unroll
        for (int i = 0; i < 4; ++i) {
            const int r = i * 32 + w * 8 + rloc;
            gl_lds16(A + (size_t)(row0 + r) * 1024 + kt + csrc,
                     smem + i * 4096 + w * 1024);
            gl_lds16(W + (size_t)(col0 + r) * 1024 + kt + csrc,
                     smem + 16384 + i * 4096 + w * 1024);
        }
        __syncthreads();

        #pragma unroll
        for (int ks = 0; ks < 2; ++ks) {
            bf16x8 a[4], b[4];
            #pragma unroll
            for (int mi = 0; mi < 4; ++mi) {
                const int r = wr * 64 + mi * 16 + c;
                a[mi] = *(const bf16x8*)(smem + r * 128 + (((ks * 4 + g) ^ (r & 7)) * 16));
            }
            #pragma unroll
            for (int ni = 0; ni < 4; ++ni) {
                const int r = wc * 64 + ni * 16 + c;
                b[ni] = *(const bf16x8*)(smem + 16384 + r * 128 + (((ks * 4 + g) ^ (r & 7)) * 16));
            }
            #pragma unroll
            for (int mi = 0; mi < 4; ++mi)
                #pragma unroll
                for (int ni = 0; ni < 4; ++ni)
                    acc[mi][ni] = __builtin_amdgcn_mfma_f32_16x16x32_bf16(
                        a[mi], b[ni], acc[mi][ni], 0, 0, 0);
        }
        __syncthreads();
    }

    #pragma unroll
    for (int mi = 0; mi < 4; ++mi) {
        #pragma unroll
        for (int ni = 0; ni < 4; ++ni) {
            const int col = col0 + wc * 64 + ni * 16 + c;
            const float bv = bias[col];
            #pragma unroll
            for (int j = 0; j < 4; ++j) {
                const int row = row0 + wr * 64 + mi * 16 + 4 * g + j;
                float v = acc[mi][ni][j] + bv;
                if (MODE == 1) {
                    fo[(size_t)row * 1024 + col] = v;
                } else {
                    const int sec = col >> 10;          // 0=q 1=k 2=v
                    const int d = col & 1023;
                    const int h = d >> 6, dk = d & 63;
                    const int b_ = row >> 11, n = row & 2047;
                    const int bh = b_ * 16 + h;
                    if (sec == 0)
                        qo[((size_t)(bh * 2048 + n) << 6) + dk] = bfbits(v * QSCALE);
                    else if (sec == 1)
                        ko[((size_t)(bh * 2048 + n) << 6) + dk] = bfbits(v);
                    else
                        vto[(size_t)(bh * 64 + dk) * 2048 + n] = bfbits(v);
                }
            }
        }
    }
}

// Flash attention, LDS-staged K/V shared by 4 waves. log2-domain online softmax.
// Q,K: [32][2048][64] bf16 (Q pre-scaled by QSCALE). Vt: [32][64][2048] bf16.
// O: [4096][1024] bf16 (row = b*2048+n, col = h*64+dk).
// Block: 4 waves x 16 q-rows = 64 q-rows. kv tiles of 64, double-buffered in LDS.
// LDS layout (bytes): K dbuf [0,16K), V dbuf [16K,32K), P per-wave [32K,40K).
__global__ __launch_bounds__(256, 4) void attn_flash(
    const unsigned short* __restrict__ Q,
    const unsigned short* __restrict__ K,
    const unsigned short* __restrict__ Vt,
    unsigned short* __restrict__ O) {
    __shared__ __attribute__((aligned(128))) unsigned char smem[40960];
    const int lane = threadIdx.x & 63;
    const int w = threadIdx.x >> 6;
    const int g = lane >> 4, c = lane & 15;
    const int c7 = c & 7;
    const int bh = blockIdx.y;
    const int q0 = blockIdx.x * 64 + w * 16;
    const unsigned short* Qb = Q + (size_t)bh * 2048 * 64;
    const unsigned short* Kb = K + (size_t)bh * 2048 * 64;
    const unsigned short* Vb = Vt + (size_t)bh * 64 * 2048;

    const int rloc = lane >> 3;
    const int csrc = ((lane & 7) ^ (rloc & 7)) * 8;

    const int chunkKV0 = ((0 + g) ^ c7) * 16;
    const int chunkKV1 = ((4 + g) ^ c7) * 16;

    unsigned char* Pbase = smem + 32768 + w * 2048;
    const int swzPc = (c ^ (c >> 3)) & 7;

    bf16x8 aq[2];
    #pragma unroll
    for (int ks = 0; ks < 2; ++ks)
        aq[ks] = *(const bf16x8*)(Qb + (size_t)(q0 + c) * 64 + ks * 32 + 8 * g);

    f32x4 o[4] = {};
    float m_run[4], l_run[4];
    #pragma unroll
    for (int j = 0; j < 4; ++j) { m_run[j] = -1e30f; l_run[j] = 0.f; }

    bf16x8 onesf;
    #pragma unroll
    for (int i = 0; i < 8; ++i) onesf[i] = (__bf16)1.0f;

    #pragma unroll
    for (int tt = 0; tt < 2; ++tt) {
        const int t = 2 * w + tt;
        const int row = 8 * t + rloc;
        gl_lds16(Kb + (size_t)row * 64 + csrc, smem + t * 1024);
        gl_lds16(Vb + (size_t)row * 2048 + csrc, smem + 16384 + t * 1024);
    }
    __syncthreads();

    int cur = 0;
    for (int kv = 0; kv < 2048; kv += 64) {
        if (kv + 64 < 2048) {
            const int nb = cur ^ 1;
            #pragma unroll
            for (int tt = 0; tt < 2; ++tt) {
                const int t = 2 * w + tt;
                const int row = 8 * t + rloc;
                gl_lds16(Kb + (size_t)(kv + 64 + row) * 64 + csrc,
                         smem + nb * 8192 + t * 1024);
                gl_lds16(Vb + (size_t)row * 2048 + (kv + 64) + csrc,
                         smem + 16384 + nb * 8192 + t * 1024);
            }
        }

        const unsigned char* Kt = smem + cur * 8192;
        const unsigned char* Vtb = smem + 16384 + cur * 8192;

        // QK^T (log2 domain): S[q=4g+j][kv = nj*16+c]
        f32x4 s[4] = {};
        #pragma unroll
        for (int nj = 0; nj < 4; ++nj) {
            bf16x8 bk0 = *(const bf16x8*)(Kt + nj * 2048 + c * 128 + chunkKV0);
            bf16x8 bk1 = *(const bf16x8*)(Kt + nj * 2048 + c * 128 + chunkKV1);
            s[nj] = __builtin_amdgcn_mfma_f32_16x16x32_bf16(aq[0], bk0, s[nj], 0, 0, 0);
            s[nj] = __builtin_amdgcn_mfma_f32_16x16x32_bf16(aq[1], bk1, s[nj], 0, 0, 0);
        }

        // row max (16 c-lanes per row)
        float mx[4];
        #pragma unroll
        for (int j = 0; j < 4; ++j) {
            float m0 = fmaxf(fmaxf(s[0][j], s[1][j]), fmaxf(s[2][j], s[3][j]));
            #pragma unroll
            for (int msk = 1; msk <= 8; msk <<= 1)
                m0 = fmaxf(m0, __shfl_xor(m0, msk));
            mx[j] = m0;
        }
        // defer-rescale (T13): only rescale when max grew by > 8 (log2 units)
        const bool grow = (mx[0] > m_run[0] + 8.f) || (mx[1] > m_run[1] + 8.f) ||
                          (mx[2] > m_run[2] + 8.f) || (mx[3] > m_run[3] + 8.f);
        if (__any((int)grow)) {
            #pragma unroll
            for (int j = 0; j < 4; ++j) {
                const float mnew = fmaxf(m_run[j], mx[j]);
                const float sc = __builtin_amdgcn_exp2f(m_run[j] - mnew);
                m_run[j] = mnew;
                l_run[j] *= sc;
                #pragma unroll
                for (int ni = 0; ni < 4; ++ni)
                    o[ni][j] *= sc;
            }
        }
        // P = 2^(s - m)
        #pragma unroll
        for (int nj = 0; nj < 4; ++nj)
            #pragma unroll
            for (int j = 0; j < 4; ++j)
                s[nj][j] = __builtin_amdgcn_exp2f(s[nj][j] - m_run[j]);

        // P -> LDS (swizzled [16][64])
        #pragma unroll
        for (int nj = 0; nj < 4; ++nj) {
            #pragma unroll
            for (int j = 0; j < 4; ++j) {
                const int r = 4 * g + j;
                const int swr = (r ^ (r >> 3)) & 7;
                *(unsigned short*)(Pbase + r * 128 + (((2 * nj + (c >> 3)) ^ swr) * 16) + c7 * 2)
                    = bfbits(s[nj][j]);
            }
        }

        // PV + row-sum via ones-MFMA
        f32x4 lt = {};
        #pragma unroll
        for (int ks = 0; ks < 2; ++ks) {
            bf16x8 ap = *(const bf16x8*)(Pbase + c * 128 + (((ks * 4 + g) ^ swzPc) * 16));
            const int ck = ks ? chunkKV1 : chunkKV0;
            #pragma unroll
            for (int ni = 0; ni < 4; ++ni) {
                bf16x8 bv = *(const bf16x8*)(Vtb + ni * 2048 + c * 128 + ck);
                o[ni] = __builtin_amdgcn_mfma_f32_16x16x32_bf16(ap, bv, o[ni], 0, 0, 0);
            }
            lt = __builtin_amdgcn_mfma_f32_16x16x32_bf16(ap, onesf, lt, 0, 0, 0);
        }
        #pragma unroll
        for (int j = 0; j < 4; ++j)
            l_run[j] += lt[j];

        __syncthreads();
        cur ^= 1;
    }

    const int b_ = bh >> 4, h = bh & 15;
    #pragma unroll
    for (int ni = 0; ni < 4; ++ni) {
        #pragma unroll
        for (int j = 0; j < 4; ++j) {
            const int row = b_ * 2048 + q0 + 4 * g + j;
            const int col = h * 64 + ni * 16 + c;
            O[(size_t)row * 1024 + col] = bfbits(o[ni][j] / l_run[j]);
        }
    }
}

extern "C" void kernel_launch(void* const* d_in, const int* in_sizes, int n_in,
                              void* d_out, int out_size, void* d_ws, size_t ws_size,
                              hipStream_t stream) {
    const float* x     = (const float*)d_in[0];
    const float* qkv_w = (const float*)d_in[1];
    const float* qkv_b = (const float*)d_in[2];
    const float* out_w = (const float*)d_in[3];
    const float* out_b = (const float*)d_in[4];
    float* out = (float*)d_out;

    char* ws = (char*)d_ws;
    unsigned short* xb   = (unsigned short*)(ws);              //  8 MB (reused as attn-out)
    unsigned short* wqkv = (unsigned short*)(ws + (8u  << 20)); //  6 MB
    unsigned short* wout = (unsigned short*)(ws + (14u << 20)); //  2 MB
    unsigned short* qb   = (unsigned short*)(ws + (16u << 20)); //  8 MB
    unsigned short* kb   = (unsigned short*)(ws + (24u << 20)); //  8 MB
    unsigned short* vtb  = (unsigned short*)(ws + (32u << 20)); //  8 MB  (total 40 MB)

    cvt_f32_bf16_v4<<<2048, 256, 0, stream>>>((const float4*)x,     (ushort4*)xb,   4096 * 1024 / 4);
    cvt_f32_bf16_v4<<<2048, 256, 0, stream>>>((const float4*)qkv_w, (ushort4*)wqkv, 3072 * 1024 / 4);
    cvt_f32_bf16_v4<<<1024, 256, 0, stream>>>((const float4*)out_w, (ushort4*)wout, 1024 * 1024 / 4);

    gemm_mfma<0><<<dim3(32, 24), 256, 0, stream>>>(xb, wqkv, qkv_b, qb, kb, vtb, nullptr);

    unsigned short* ao = xb;  // xb no longer needed; reuse for attention output
    attn_flash<<<dim3(32, 32), 256, 0, stream>>>(qb, kb, vtb, ao);

    gemm_mfma<1><<<dim3(32, 8), 256, 0, stream>>>(ao, wout, out_b, nullptr, nullptr, nullptr, out);
}

// Round 6
// 136.203 us; speedup vs baseline: 2.7688x; 1.1325x over previous
//
#include <hip/hip_runtime.h>
#include <hip/hip_bf16.h>

// MultiHeadAttention: x(2,2048,1024) fp32 -> out(2,2048,1024) fp32
// Pipeline: cvt->bf16; QKV GEMM (LDS-staged mfma) -> q(*0.125*log2e),k,v^T; flash attn
// (LDS-staged K/V, log2-domain softmax, deferred max-reduce); out GEMM.

typedef __bf16 bf16x8 __attribute__((ext_vector_type(8)));
typedef float f32x4 __attribute__((ext_vector_type(4)));

#define QSCALE 0.18033688011112042f  // 0.125 * log2(e): QK^T lands in log2 domain

__device__ __forceinline__ unsigned short bfbits(float f) {
    union { __bf16 h; unsigned short u; } cv;
    cv.h = (__bf16)f;
    return cv.u;
}

__device__ __forceinline__ void gl_lds16(const void* g, void* l) {
    __builtin_amdgcn_global_load_lds(
        (__attribute__((address_space(1))) const unsigned int*)g,
        (__attribute__((address_space(3))) unsigned int*)l, 16, 0, 0);
}

__global__ void cvt_f32_bf16_v4(const float4* __restrict__ src,
                                ushort4* __restrict__ dst, int n4) {
    int i = blockIdx.x * blockDim.x + threadIdx.x;
    int stride = gridDim.x * blockDim.x;
    for (; i < n4; i += stride) {
        float4 f = src[i];
        ushort4 o;
        o.x = bfbits(f.x); o.y = bfbits(f.y); o.z = bfbits(f.z); o.w = bfbits(f.w);
        dst[i] = o;
    }
}

// C = A(M x 1024) @ W(N x 1024)^T + bias. 128x128 block tile, 4 waves (2x2) of 64x64.
// m97 structure: BK=64 single-buffer LDS, global_load_lds w16 staging, 2-barrier K-loop.
// LDS: As [0,16K) = [128 rows][8 chunks16B, pos = chunk^(row&7)]; Bs [16K,32K) same.
// MODE 0: N=3072, scatter to q (scaled QSCALE), k, vt (v transposed [bh][dk][n]) as bf16.
// MODE 1: N=1024, fp32 out row-major.
template<int MODE>
__global__ __launch_bounds__(256, 3) void gemm_mfma(
    const unsigned short* __restrict__ A,
    const unsigned short* __restrict__ W,
    const float* __restrict__ bias,
    unsigned short* __restrict__ qo,
    unsigned short* __restrict__ ko,
    unsigned short* __restrict__ vto,
    float* __restrict__ fo) {
    __shared__ __attribute__((aligned(128))) unsigned char smem[32768];
    const int lane = threadIdx.x & 63;
    const int w = threadIdx.x >> 6;
    const int g = lane >> 4, c = lane & 15;
    const int wr = w >> 1, wc = w & 1;
    const int row0 = blockIdx.x * 128;
    const int col0 = blockIdx.y * 128;

    const int rloc = lane >> 3;                      // 0..7
    const int csrc = ((lane & 7) ^ rloc) * 8;        // pre-swizzled source chunk (elements)

    f32x4 acc[4][4] = {};

    for (int kt = 0; kt < 1024; kt += 64) {
        #pragma unroll
        for (int i = 0; i < 4; ++i) {
            const int r = i * 32 + w * 8 + rloc;
            gl_lds16(A + (size_t)(row0 + r) * 1024 + kt + csrc,
                     smem + i * 4096 + w * 1024);
            gl_lds16(W + (size_t)(col0 + r) * 1024 + kt + csrc,
                     smem + 16384 + i * 4096 + w * 1024);
        }
        __syncthreads();

        #pragma unroll
        for (int ks = 0; ks < 2; ++ks) {
            bf16x8 a[4], b[4];
            #pragma unroll
            for (int mi = 0; mi < 4; ++mi) {
                const int r = wr * 64 + mi * 16 + c;
                a[mi] = *(const bf16x8*)(smem + r * 128 + (((ks * 4 + g) ^ (r & 7)) * 16));
            }
            #pragma unroll
            for (int ni = 0; ni < 4; ++ni) {
                const int r = wc * 64 + ni * 16 + c;
                b[ni] = *(const bf16x8*)(smem + 16384 + r * 128 + (((ks * 4 + g) ^ (r & 7)) * 16));
            }
            #pragma unroll
            for (int mi = 0; mi < 4; ++mi)
                #pragma unroll
                for (int ni = 0; ni < 4; ++ni)
                    acc[mi][ni] = __builtin_amdgcn_mfma_f32_16x16x32_bf16(
                        a[mi], b[ni], acc[mi][ni], 0, 0, 0);
        }
        __syncthreads();
    }

    #pragma unroll
    for (int mi = 0; mi < 4; ++mi) {
        #pragma unroll
        for (int ni = 0; ni < 4; ++ni) {
            const int col = col0 + wc * 64 + ni * 16 + c;
            const float bv = bias[col];
            #pragma unroll
            for (int j = 0; j < 4; ++j) {
                const int row = row0 + wr * 64 + mi * 16 + 4 * g + j;
                float v = acc[mi][ni][j] + bv;
                if (MODE == 1) {
                    fo[(size_t)row * 1024 + col] = v;
                } else {
                    const int sec = col >> 10;          // 0=q 1=k 2=v
                    const int d = col & 1023;
                    const int h = d >> 6, dk = d & 63;
                    const int b_ = row >> 11, n = row & 2047;
                    const int bh = b_ * 16 + h;
                    if (sec == 0)
                        qo[((size_t)(bh * 2048 + n) << 6) + dk] = bfbits(v * QSCALE);
                    else if (sec == 1)
                        ko[((size_t)(bh * 2048 + n) << 6) + dk] = bfbits(v);
                    else
                        vto[(size_t)(bh * 64 + dk) * 2048 + n] = bfbits(v);
                }
            }
        }
    }
}

// Flash attention, LDS-staged K/V shared by 4 waves. log2-domain online softmax with
// fully deferred max-reduce: common path has NO cross-lane reduction (per-lane partial
// max + wave __any bound check); full shfl reduce + rescale only when bound exceeded.
// Q,K: [32][2048][64] bf16 (Q pre-scaled by QSCALE). Vt: [32][64][2048] bf16.
// O: [4096][1024] bf16 (row = b*2048+n, col = h*64+dk).
// Block: 4 waves x 16 q-rows = 64 q-rows. kv tiles of 64, double-buffered in LDS.
// LDS layout (bytes): K dbuf [0,16K), V dbuf [16K,32K), P per-wave [32K,40K).
__global__ __launch_bounds__(256, 4) void attn_flash(
    const unsigned short* __restrict__ Q,
    const unsigned short* __restrict__ K,
    const unsigned short* __restrict__ Vt,
    unsigned short* __restrict__ O) {
    __shared__ __attribute__((aligned(128))) unsigned char smem[40960];
    const int lane = threadIdx.x & 63;
    const int w = threadIdx.x >> 6;
    const int g = lane >> 4, c = lane & 15;
    const int c7 = c & 7;
    const int bh = blockIdx.y;
    const int q0 = blockIdx.x * 64 + w * 16;
    const unsigned short* Qb = Q + (size_t)bh * 2048 * 64;
    const unsigned short* Kb = K + (size_t)bh * 2048 * 64;
    const unsigned short* Vb = Vt + (size_t)bh * 64 * 2048;

    const int rloc = lane >> 3;
    const int csrc = ((lane & 7) ^ (rloc & 7)) * 8;

    const int chunkKV0 = ((0 + g) ^ c7) * 16;
    const int chunkKV1 = ((4 + g) ^ c7) * 16;

    unsigned char* Pbase = smem + 32768 + w * 2048;
    const int swzPc = (c ^ (c >> 3)) & 7;

    bf16x8 aq[2];
    #pragma unroll
    for (int ks = 0; ks < 2; ++ks)
        aq[ks] = *(const bf16x8*)(Qb + (size_t)(q0 + c) * 64 + ks * 32 + 8 * g);

    f32x4 o[4] = {};
    float m_run[4], l_run[4];
    #pragma unroll
    for (int j = 0; j < 4; ++j) { m_run[j] = -1e30f; l_run[j] = 0.f; }

    bf16x8 onesf;
    #pragma unroll
    for (int i = 0; i < 8; ++i) onesf[i] = (__bf16)1.0f;

    #pragma unroll
    for (int tt = 0; tt < 2; ++tt) {
        const int t = 2 * w + tt;
        const int row = 8 * t + rloc;
        gl_lds16(Kb + (size_t)row * 64 + csrc, smem + t * 1024);
        gl_lds16(Vb + (size_t)row * 2048 + csrc, smem + 16384 + t * 1024);
    }
    __syncthreads();

    int cur = 0;
    for (int kv = 0; kv < 2048; kv += 64) {
        if (kv + 64 < 2048) {
            const int nb = cur ^ 1;
            #pragma unroll
            for (int tt = 0; tt < 2; ++tt) {
                const int t = 2 * w + tt;
                const int row = 8 * t + rloc;
                gl_lds16(Kb + (size_t)(kv + 64 + row) * 64 + csrc,
                         smem + nb * 8192 + t * 1024);
                gl_lds16(Vb + (size_t)row * 2048 + (kv + 64) + csrc,
                         smem + 16384 + nb * 8192 + t * 1024);
            }
        }

        const unsigned char* Kt = smem + cur * 8192;
        const unsigned char* Vtb = smem + 16384 + cur * 8192;

        // QK^T (log2 domain): S[q=4g+j][kv = nj*16+c]
        f32x4 s[4] = {};
        __builtin_amdgcn_s_setprio(1);
        #pragma unroll
        for (int nj = 0; nj < 4; ++nj) {
            bf16x8 bk0 = *(const bf16x8*)(Kt + nj * 2048 + c * 128 + chunkKV0);
            bf16x8 bk1 = *(const bf16x8*)(Kt + nj * 2048 + c * 128 + chunkKV1);
            s[nj] = __builtin_amdgcn_mfma_f32_16x16x32_bf16(aq[0], bk0, s[nj], 0, 0, 0);
            s[nj] = __builtin_amdgcn_mfma_f32_16x16x32_bf16(aq[1], bk1, s[nj], 0, 0, 0);
        }
        __builtin_amdgcn_s_setprio(0);

        // per-lane partial row max (no cross-lane reduce on the common path)
        float pmax[4];
        #pragma unroll
        for (int j = 0; j < 4; ++j)
            pmax[j] = fmaxf(fmaxf(s[0][j], s[1][j]), fmaxf(s[2][j], s[3][j]));

        // deferred max: if no lane's partial exceeds m_run+8, true row max <= m_run+8
        // and P = 2^(s-m_run) <= 256 (safe). Else do the full reduce + rescale.
        const bool grow = (pmax[0] > m_run[0] + 8.f) || (pmax[1] > m_run[1] + 8.f) ||
                          (pmax[2] > m_run[2] + 8.f) || (pmax[3] > m_run[3] + 8.f);
        if (__any((int)grow)) {
            #pragma unroll
            for (int j = 0; j < 4; ++j) {
                float m0 = pmax[j];
                #pragma unroll
                for (int msk = 1; msk <= 8; msk <<= 1)
                    m0 = fmaxf(m0, __shfl_xor(m0, msk));
                const float mnew = fmaxf(m_run[j], m0);
                const float sc = __builtin_amdgcn_exp2f(m_run[j] - mnew);
                m_run[j] = mnew;
                l_run[j] *= sc;
                #pragma unroll
                for (int ni = 0; ni < 4; ++ni)
                    o[ni][j] *= sc;
            }
        }

        // P = 2^(s - m)
        #pragma unroll
        for (int nj = 0; nj < 4; ++nj)
            #pragma unroll
            for (int j = 0; j < 4; ++j)
                s[nj][j] = __builtin_amdgcn_exp2f(s[nj][j] - m_run[j]);

        // P -> LDS (swizzled [16][64])
        #pragma unroll
        for (int nj = 0; nj < 4; ++nj) {
            #pragma unroll
            for (int j = 0; j < 4; ++j) {
                const int r = 4 * g + j;
                const int swr = (r ^ (r >> 3)) & 7;
                *(unsigned short*)(Pbase + r * 128 + (((2 * nj + (c >> 3)) ^ swr) * 16) + c7 * 2)
                    = bfbits(s[nj][j]);
            }
        }

        // PV + row-sum via ones-MFMA
        f32x4 lt = {};
        __builtin_amdgcn_s_setprio(1);
        #pragma unroll
        for (int ks = 0; ks < 2; ++ks) {
            bf16x8 ap = *(const bf16x8*)(Pbase + c * 128 + (((ks * 4 + g) ^ swzPc) * 16));
            const int ck = ks ? chunkKV1 : chunkKV0;
            #pragma unroll
            for (int ni = 0; ni < 4; ++ni) {
                bf16x8 bv = *(const bf16x8*)(Vtb + ni * 2048 + c * 128 + ck);
                o[ni] = __builtin_amdgcn_mfma_f32_16x16x32_bf16(ap, bv, o[ni], 0, 0, 0);
            }
            lt = __builtin_amdgcn_mfma_f32_16x16x32_bf16(ap, onesf, lt, 0, 0, 0);
        }
        __builtin_amdgcn_s_setprio(0);
        #pragma unroll
        for (int j = 0; j < 4; ++j)
            l_run[j] += lt[j];

        __syncthreads();
        cur ^= 1;
    }

    // final: exact normalization (l_run components consistent with deferred m_run)
    const int b_ = bh >> 4, h = bh & 15;
    #pragma unroll
    for (int ni = 0; ni < 4; ++ni) {
        #pragma unroll
        for (int j = 0; j < 4; ++j) {
            const int row = b_ * 2048 + q0 + 4 * g + j;
            const int col = h * 64 + ni * 16 + c;
            O[(size_t)row * 1024 + col] = bfbits(o[ni][j] / l_run[j]);
        }
    }
}

extern "C" void kernel_launch(void* const* d_in, const int* in_sizes, int n_in,
                              void* d_out, int out_size, void* d_ws, size_t ws_size,
                              hipStream_t stream) {
    const float* x     = (const float*)d_in[0];
    const float* qkv_w = (const float*)d_in[1];
    const float* qkv_b = (const float*)d_in[2];
    const float* out_w = (const float*)d_in[3];
    const float* out_b = (const float*)d_in[4];
    float* out = (float*)d_out;

    char* ws = (char*)d_ws;
    unsigned short* xb   = (unsigned short*)(ws);              //  8 MB (reused as attn-out)
    unsigned short* wqkv = (unsigned short*)(ws + (8u  << 20)); //  6 MB
    unsigned short* wout = (unsigned short*)(ws + (14u << 20)); //  2 MB
    unsigned short* qb   = (unsigned short*)(ws + (16u << 20)); //  8 MB
    unsigned short* kb   = (unsigned short*)(ws + (24u << 20)); //  8 MB
    unsigned short* vtb  = (unsigned short*)(ws + (32u << 20)); //  8 MB  (total 40 MB)

    cvt_f32_bf16_v4<<<2048, 256, 0, stream>>>((const float4*)x,     (ushort4*)xb,   4096 * 1024 / 4);
    cvt_f32_bf16_v4<<<2048, 256, 0, stream>>>((const float4*)qkv_w, (ushort4*)wqkv, 3072 * 1024 / 4);
    cvt_f32_bf16_v4<<<1024, 256, 0, stream>>>((const float4*)out_w, (ushort4*)wout, 1024 * 1024 / 4);

    gemm_mfma<0><<<dim3(32, 24), 256, 0, stream>>>(xb, wqkv, qkv_b, qb, kb, vtb, nullptr);

    unsigned short* ao = xb;  // xb no longer needed; reuse for attention output
    attn_flash<<<dim3(32, 32), 256, 0, stream>>>(qb, kb, vtb, ao);

    gemm_mfma<1><<<dim3(32, 8), 256, 0, stream>>>(ao, wout, out_b, nullptr, nullptr, nullptr, out);
}

// Round 7
// 130.691 us; speedup vs baseline: 2.8856x; 1.0422x over previous
//
#include <hip/hip_runtime.h>
#include <hip/hip_bf16.h>

// MultiHeadAttention: x(2,2048,1024) fp32 -> out(2,2048,1024) fp32
// Pipeline: cvt->bf16; QKV GEMM (LDS-staged mfma) -> q(*0.125*log2e),k,v^T; flash attn
// (LDS K/V, swapped QK^T, in-register P -> K=16 PV MFMAs, deferred max); out GEMM.

typedef __bf16 bf16x8 __attribute__((ext_vector_type(8)));
typedef __bf16 bf16x4 __attribute__((ext_vector_type(4)));
typedef short short4v __attribute__((ext_vector_type(4)));
typedef float f32x4 __attribute__((ext_vector_type(4)));

#define QSCALE 0.18033688011112042f  // 0.125 * log2(e): QK^T lands in log2 domain

__device__ __forceinline__ unsigned short bfbits(float f) {
    union { __bf16 h; unsigned short u; } cv;
    cv.h = (__bf16)f;
    return cv.u;
}

__device__ __forceinline__ f32x4 mfma16(bf16x4 a, bf16x4 b, f32x4 c) {
#if __has_builtin(__builtin_amdgcn_mfma_f32_16x16x16bf16_1k)
    union { bf16x4 h; short4v s; } ua, ub;
    ua.h = a; ub.h = b;
    return __builtin_amdgcn_mfma_f32_16x16x16bf16_1k(ua.s, ub.s, c, 0, 0, 0);
#else
    f32x4 d = c;
    asm volatile("v_mfma_f32_16x16x16_bf16 %0, %1, %2, %0"
                 : "+v"(d) : "v"(a), "v"(b));
    return d;
#endif
}

__device__ __forceinline__ void gl_lds16(const void* g, void* l) {
    __builtin_amdgcn_global_load_lds(
        (__attribute__((address_space(1))) const unsigned int*)g,
        (__attribute__((address_space(3))) unsigned int*)l, 16, 0, 0);
}

__global__ void cvt_f32_bf16_v4(const float4* __restrict__ src,
                                ushort4* __restrict__ dst, int n4) {
    int i = blockIdx.x * blockDim.x + threadIdx.x;
    int stride = gridDim.x * blockDim.x;
    for (; i < n4; i += stride) {
        float4 f = src[i];
        ushort4 o;
        o.x = bfbits(f.x); o.y = bfbits(f.y); o.z = bfbits(f.z); o.w = bfbits(f.w);
        dst[i] = o;
    }
}

// C = A(M x 1024) @ W(N x 1024)^T + bias. 128x128 block tile, 4 waves (2x2) of 64x64.
// m97 structure: BK=64 single-buffer LDS, global_load_lds w16 staging, 2-barrier K-loop.
// MODE 0: N=3072, scatter to q (scaled QSCALE), k, vt (v transposed [bh][dk][n]) as bf16.
// MODE 1: N=1024, fp32 out row-major.
template<int MODE>
__global__ __launch_bounds__(256, 3) void gemm_mfma(
    const unsigned short* __restrict__ A,
    const unsigned short* __restrict__ W,
    const float* __restrict__ bias,
    unsigned short* __restrict__ qo,
    unsigned short* __restrict__ ko,
    unsigned short* __restrict__ vto,
    float* __restrict__ fo) {
    __shared__ __attribute__((aligned(128))) unsigned char smem[32768];
    const int lane = threadIdx.x & 63;
    const int w = threadIdx.x >> 6;
    const int g = lane >> 4, c = lane & 15;
    const int wr = w >> 1, wc = w & 1;
    const int row0 = blockIdx.x * 128;
    const int col0 = blockIdx.y * 128;

    const int rloc = lane >> 3;                      // 0..7
    const int csrc = ((lane & 7) ^ rloc) * 8;        // pre-swizzled source chunk (elements)

    f32x4 acc[4][4] = {};

    for (int kt = 0; kt < 1024; kt += 64) {
        #pragma unroll
        for (int i = 0; i < 4; ++i) {
            const int r = i * 32 + w * 8 + rloc;
            gl_lds16(A + (size_t)(row0 + r) * 1024 + kt + csrc,
                     smem + i * 4096 + w * 1024);
            gl_lds16(W + (size_t)(col0 + r) * 1024 + kt + csrc,
                     smem + 16384 + i * 4096 + w * 1024);
        }
        __syncthreads();

        #pragma unroll
        for (int ks = 0; ks < 2; ++ks) {
            bf16x8 a[4], b[4];
            #pragma unroll
            for (int mi = 0; mi < 4; ++mi) {
                const int r = wr * 64 + mi * 16 + c;
                a[mi] = *(const bf16x8*)(smem + r * 128 + (((ks * 4 + g) ^ (r & 7)) * 16));
            }
            #pragma unroll
            for (int ni = 0; ni < 4; ++ni) {
                const int r = wc * 64 + ni * 16 + c;
                b[ni] = *(const bf16x8*)(smem + 16384 + r * 128 + (((ks * 4 + g) ^ (r & 7)) * 16));
            }
            #pragma unroll
            for (int mi = 0; mi < 4; ++mi)
                #pragma unroll
                for (int ni = 0; ni < 4; ++ni)
                    acc[mi][ni] = __builtin_amdgcn_mfma_f32_16x16x32_bf16(
                        a[mi], b[ni], acc[mi][ni], 0, 0, 0);
        }
        __syncthreads();
    }

    #pragma unroll
    for (int mi = 0; mi < 4; ++mi) {
        #pragma unroll
        for (int ni = 0; ni < 4; ++ni) {
            const int col = col0 + wc * 64 + ni * 16 + c;
            const float bv = bias[col];
            #pragma unroll
            for (int j = 0; j < 4; ++j) {
                const int row = row0 + wr * 64 + mi * 16 + 4 * g + j;
                float v = acc[mi][ni][j] + bv;
                if (MODE == 1) {
                    fo[(size_t)row * 1024 + col] = v;
                } else {
                    const int sec = col >> 10;          // 0=q 1=k 2=v
                    const int d = col & 1023;
                    const int h = d >> 6, dk = d & 63;
                    const int b_ = row >> 11, n = row & 2047;
                    const int bh = b_ * 16 + h;
                    if (sec == 0)
                        qo[((size_t)(bh * 2048 + n) << 6) + dk] = bfbits(v * QSCALE);
                    else if (sec == 1)
                        ko[((size_t)(bh * 2048 + n) << 6) + dk] = bfbits(v);
                    else
                        vto[(size_t)(bh * 64 + dk) * 2048 + n] = bfbits(v);
                }
            }
        }
    }
}

// Flash attention, LDS-staged K/V shared by 4 waves. Swapped QK^T: s=mfma(K,Q) puts
// P[q=c][kv=16nj+4g+j] per-lane -- exactly the 16x16x16 A-fragment (k=4g+i), so PV
// runs on in-register P with no LDS round-trip. log2-domain, deferred max (scalar m).
// Q,K: [32][2048][64] bf16 (Q pre-scaled by QSCALE). Vt: [32][64][2048] bf16.
// O: [4096][1024] bf16 (row = b*2048+n, col = h*64+dk).
// Block: 4 waves x 16 q-rows = 64 q-rows. kv tiles of 64, double-buffered in LDS.
// LDS (bytes): K dbuf [0,16K), V dbuf [16K,32K). 32KB -> 4 blocks/CU.
__global__ __launch_bounds__(256, 4) void attn_flash(
    const unsigned short* __restrict__ Q,
    const unsigned short* __restrict__ K,
    const unsigned short* __restrict__ Vt,
    unsigned short* __restrict__ O) {
    __shared__ __attribute__((aligned(128))) unsigned char smem[32768];
    const int lane = threadIdx.x & 63;
    const int w = threadIdx.x >> 6;
    const int g = lane >> 4, c = lane & 15;
    const int c7 = c & 7;
    const int bh = blockIdx.y;
    const int q0 = blockIdx.x * 64 + w * 16;
    const unsigned short* Qb = Q + (size_t)bh * 2048 * 64;
    const unsigned short* Kb = K + (size_t)bh * 2048 * 64;
    const unsigned short* Vb = Vt + (size_t)bh * 64 * 2048;

    const int rloc = lane >> 3;
    const int csrc = ((lane & 7) ^ (rloc & 7)) * 8;

    const int chunkKV0 = ((0 + g) ^ c7) * 16;
    const int chunkKV1 = ((4 + g) ^ c7) * 16;
    const int ghalf = (g >> 1);            // for V b64 reads
    const int gsub = (g & 1) * 8;

    bf16x8 aq[2];
    #pragma unroll
    for (int ks = 0; ks < 2; ++ks)
        aq[ks] = *(const bf16x8*)(Qb + (size_t)(q0 + c) * 64 + ks * 32 + 8 * g);

    f32x4 o[4] = {};
    f32x4 l_run = {};
    float m_run = -1e30f;                  // running max for q-row c (per lane)

    bf16x4 ones4;
    #pragma unroll
    for (int i = 0; i < 4; ++i) ones4[i] = (__bf16)1.0f;

    #pragma unroll
    for (int tt = 0; tt < 2; ++tt) {
        const int t = 2 * w + tt;
        const int row = 8 * t + rloc;
        gl_lds16(Kb + (size_t)row * 64 + csrc, smem + t * 1024);
        gl_lds16(Vb + (size_t)row * 2048 + csrc, smem + 16384 + t * 1024);
    }
    __syncthreads();

    int cur = 0;
    for (int kv = 0; kv < 2048; kv += 64) {
        if (kv + 64 < 2048) {
            const int nb = cur ^ 1;
            #pragma unroll
            for (int tt = 0; tt < 2; ++tt) {
                const int t = 2 * w + tt;
                const int row = 8 * t + rloc;
                gl_lds16(Kb + (size_t)(kv + 64 + row) * 64 + csrc,
                         smem + nb * 8192 + t * 1024);
                gl_lds16(Vb + (size_t)row * 2048 + (kv + 64) + csrc,
                         smem + 16384 + nb * 8192 + t * 1024);
            }
        }

        const unsigned char* Kt = smem + cur * 8192;
        const unsigned char* Vtb = smem + 16384 + cur * 8192;

        // swapped QK^T: s[nj] = mfma(A=K, B=Q) -> lane holds P[q=c][kv=16nj+4g+j]
        f32x4 s[4] = {};
        __builtin_amdgcn_s_setprio(1);
        #pragma unroll
        for (int nj = 0; nj < 4; ++nj) {
            bf16x8 bk0 = *(const bf16x8*)(Kt + nj * 2048 + c * 128 + chunkKV0);
            bf16x8 bk1 = *(const bf16x8*)(Kt + nj * 2048 + c * 128 + chunkKV1);
            s[nj] = __builtin_amdgcn_mfma_f32_16x16x32_bf16(bk0, aq[0], s[nj], 0, 0, 0);
            s[nj] = __builtin_amdgcn_mfma_f32_16x16x32_bf16(bk1, aq[1], s[nj], 0, 0, 0);
        }
        __builtin_amdgcn_s_setprio(0);

        // per-lane partial max over this lane's 16 P values (all belong to q-row c)
        float pmax = s[0][0];
        #pragma unroll
        for (int nj = 0; nj < 4; ++nj)
            #pragma unroll
            for (int j = 0; j < 4; ++j)
                pmax = fmaxf(pmax, s[nj][j]);

        // deferred max: trigger full cross-g reduce + rescale only on growth > 8
        if (__any((int)(pmax > m_run + 8.f))) {
            float rm = pmax;
            rm = fmaxf(rm, __shfl_xor(rm, 16));
            rm = fmaxf(rm, __shfl_xor(rm, 32));
            const float mnew = fmaxf(m_run, rm);
            const float sc = __builtin_amdgcn_exp2f(m_run - mnew);
            m_run = mnew;
            #pragma unroll
            for (int j = 0; j < 4; ++j) {
                const float scj = __shfl(sc, 4 * g + j);   // sc for q-row 4g+j
                l_run[j] *= scj;
                #pragma unroll
                for (int ni = 0; ni < 4; ++ni)
                    o[ni][j] *= scj;
            }
        }

        // P = 2^(s - m), pack to 16x16x16 A-fragments (k = 4g+i), all in-register
        bf16x4 p[4];
        #pragma unroll
        for (int nj = 0; nj < 4; ++nj)
            #pragma unroll
            for (int j = 0; j < 4; ++j)
                p[nj][j] = (__bf16)__builtin_amdgcn_exp2f(s[nj][j] - m_run);

        // PV via K=16 MFMAs (B = V^T b64 frags) + ones-MFMA row sums
        f32x4 lt = {};
        __builtin_amdgcn_s_setprio(1);
        #pragma unroll
        for (int nj = 0; nj < 4; ++nj) {
            lt = mfma16(p[nj], ones4, lt);
            #pragma unroll
            for (int ni = 0; ni < 4; ++ni) {
                bf16x4 bv = *(const bf16x4*)(Vtb + (ni * 16 + c) * 128 +
                                             (((2 * nj + ghalf) ^ c7) * 16) + gsub);
                o[ni] = mfma16(p[nj], bv, o[ni]);
            }
        }
        __builtin_amdgcn_s_setprio(0);
        l_run += lt;

        __syncthreads();
        cur ^= 1;
    }

    const int b_ = bh >> 4, h = bh & 15;
    #pragma unroll
    for (int ni = 0; ni < 4; ++ni) {
        #pragma unroll
        for (int j = 0; j < 4; ++j) {
            const int row = b_ * 2048 + q0 + 4 * g + j;
            const int col = h * 64 + ni * 16 + c;
            O[(size_t)row * 1024 + col] = bfbits(o[ni][j] / l_run[j]);
        }
    }
}

extern "C" void kernel_launch(void* const* d_in, const int* in_sizes, int n_in,
                              void* d_out, int out_size, void* d_ws, size_t ws_size,
                              hipStream_t stream) {
    const float* x     = (const float*)d_in[0];
    const float* qkv_w = (const float*)d_in[1];
    const float* qkv_b = (const float*)d_in[2];
    const float* out_w = (const float*)d_in[3];
    const float* out_b = (const float*)d_in[4];
    float* out = (float*)d_out;

    char* ws = (char*)d_ws;
    unsigned short* xb   = (unsigned short*)(ws);              //  8 MB (reused as attn-out)
    unsigned short* wqkv = (unsigned short*)(ws + (8u  << 20)); //  6 MB
    unsigned short* wout = (unsigned short*)(ws + (14u << 20)); //  2 MB
    unsigned short* qb   = (unsigned short*)(ws + (16u << 20)); //  8 MB
    unsigned short* kb   = (unsigned short*)(ws + (24u << 20)); //  8 MB
    unsigned short* vtb  = (unsigned short*)(ws + (32u << 20)); //  8 MB  (total 40 MB)

    cvt_f32_bf16_v4<<<2048, 256, 0, stream>>>((const float4*)x,     (ushort4*)xb,   4096 * 1024 / 4);
    cvt_f32_bf16_v4<<<2048, 256, 0, stream>>>((const float4*)qkv_w, (ushort4*)wqkv, 3072 * 1024 / 4);
    cvt_f32_bf16_v4<<<1024, 256, 0, stream>>>((const float4*)out_w, (ushort4*)wout, 1024 * 1024 / 4);

    gemm_mfma<0><<<dim3(32, 24), 256, 0, stream>>>(xb, wqkv, qkv_b, qb, kb, vtb, nullptr);

    unsigned short* ao = xb;  // xb no longer needed; reuse for attention output
    attn_flash<<<dim3(32, 32), 256, 0, stream>>>(qb, kb, vtb, ao);

    gemm_mfma<1><<<dim3(32, 8), 256, 0, stream>>>(ao, wout, out_b, nullptr, nullptr, nullptr, out);
}

// Round 8
// 130.461 us; speedup vs baseline: 2.8907x; 1.0018x over previous
//
#include <hip/hip_runtime.h>
#include <hip/hip_bf16.h>

// MultiHeadAttention: x(2,2048,1024) fp32 -> out(2,2048,1024) fp32
// Pipeline: fused cvt->bf16; QKV GEMM (LDS-staged mfma) -> q(*0.125*log2e),k,v^T;
// flash attn (2-wave blocks, 32 q-rows/wave, swapped QK^T, in-reg P, deferred max); out GEMM.

typedef __bf16 bf16x8 __attribute__((ext_vector_type(8)));
typedef __bf16 bf16x4 __attribute__((ext_vector_type(4)));
typedef short short4v __attribute__((ext_vector_type(4)));
typedef float f32x4 __attribute__((ext_vector_type(4)));

#define QSCALE 0.18033688011112042f  // 0.125 * log2(e): QK^T lands in log2 domain

__device__ __forceinline__ unsigned short bfbits(float f) {
    union { __bf16 h; unsigned short u; } cv;
    cv.h = (__bf16)f;
    return cv.u;
}

__device__ __forceinline__ f32x4 mfma16(bf16x4 a, bf16x4 b, f32x4 c) {
#if __has_builtin(__builtin_amdgcn_mfma_f32_16x16x16bf16_1k)
    union { bf16x4 h; short4v s; } ua, ub;
    ua.h = a; ub.h = b;
    return __builtin_amdgcn_mfma_f32_16x16x16bf16_1k(ua.s, ub.s, c, 0, 0, 0);
#else
    f32x4 d = c;
    asm volatile("v_mfma_f32_16x16x16_bf16 %0, %1, %2, %0"
                 : "+v"(d) : "v"(a), "v"(b));
    return d;
#endif
}

__device__ __forceinline__ void gl_lds16(const void* g, void* l) {
    __builtin_amdgcn_global_load_lds(
        (__attribute__((address_space(1))) const unsigned int*)g,
        (__attribute__((address_space(3))) unsigned int*)l, 16, 0, 0);
}

// Fused bf16 conversion: x (1048576 f4), qkv_w (786432 f4), out_w (262144 f4)
// into contiguous dst (ws+0: xb 8MB | ws+8M: wqkv 6MB | ws+14M: wout 2MB).
__global__ void cvt_all(const float4* __restrict__ x,
                        const float4* __restrict__ wq,
                        const float4* __restrict__ wo,
                        ushort4* __restrict__ dst) {
    int i = blockIdx.x * blockDim.x + threadIdx.x;
    const int stride = gridDim.x * blockDim.x;
    for (; i < 2097152; i += stride) {
        float4 f;
        if (i < 1048576)       f = x[i];
        else if (i < 1835008)  f = wq[i - 1048576];
        else                   f = wo[i - 1835008];
        ushort4 o;
        o.x = bfbits(f.x); o.y = bfbits(f.y); o.z = bfbits(f.z); o.w = bfbits(f.w);
        dst[i] = o;
    }
}

// C = A(M x 1024) @ W(N x 1024)^T + bias. 128x128 block tile, 4 waves (2x2) of 64x64.
// m97 structure: BK=64 single-buffer LDS, global_load_lds w16 staging, 2-barrier K-loop.
// MODE 0: N=3072, scatter to q (scaled QSCALE), k, vt (v transposed [bh][dk][n]) as bf16.
// MODE 1: N=1024, fp32 out row-major.
template<int MODE>
__global__ __launch_bounds__(256, 3) void gemm_mfma(
    const unsigned short* __restrict__ A,
    const unsigned short* __restrict__ W,
    const float* __restrict__ bias,
    unsigned short* __restrict__ qo,
    unsigned short* __restrict__ ko,
    unsigned short* __restrict__ vto,
    float* __restrict__ fo) {
    __shared__ __attribute__((aligned(128))) unsigned char smem[32768];
    const int lane = threadIdx.x & 63;
    const int w = threadIdx.x >> 6;
    const int g = lane >> 4, c = lane & 15;
    const int wr = w >> 1, wc = w & 1;
    const int row0 = blockIdx.x * 128;
    const int col0 = blockIdx.y * 128;

    const int rloc = lane >> 3;                      // 0..7
    const int csrc = ((lane & 7) ^ rloc) * 8;        // pre-swizzled source chunk (elements)

    f32x4 acc[4][4] = {};

    for (int kt = 0; kt < 1024; kt += 64) {
        #pragma unroll
        for (int i = 0; i < 4; ++i) {
            const int r = i * 32 + w * 8 + rloc;
            gl_lds16(A + (size_t)(row0 + r) * 1024 + kt + csrc,
                     smem + i * 4096 + w * 1024);
            gl_lds16(W + (size_t)(col0 + r) * 1024 + kt + csrc,
                     smem + 16384 + i * 4096 + w * 1024);
        }
        __syncthreads();

        #pragma unroll
        for (int ks = 0; ks < 2; ++ks) {
            bf16x8 a[4], b[4];
            #pragma unroll
            for (int mi = 0; mi < 4; ++mi) {
                const int r = wr * 64 + mi * 16 + c;
                a[mi] = *(const bf16x8*)(smem + r * 128 + (((ks * 4 + g) ^ (r & 7)) * 16));
            }
            #pragma unroll
            for (int ni = 0; ni < 4; ++ni) {
                const int r = wc * 64 + ni * 16 + c;
                b[ni] = *(const bf16x8*)(smem + 16384 + r * 128 + (((ks * 4 + g) ^ (r & 7)) * 16));
            }
            #pragma unroll
            for (int mi = 0; mi < 4; ++mi)
                #pragma unroll
                for (int ni = 0; ni < 4; ++ni)
                    acc[mi][ni] = __builtin_amdgcn_mfma_f32_16x16x32_bf16(
                        a[mi], b[ni], acc[mi][ni], 0, 0, 0);
        }
        __syncthreads();
    }

    #pragma unroll
    for (int mi = 0; mi < 4; ++mi) {
        #pragma unroll
        for (int ni = 0; ni < 4; ++ni) {
            const int col = col0 + wc * 64 + ni * 16 + c;
            const float bv = bias[col];
            #pragma unroll
            for (int j = 0; j < 4; ++j) {
                const int row = row0 + wr * 64 + mi * 16 + 4 * g + j;
                float v = acc[mi][ni][j] + bv;
                if (MODE == 1) {
                    fo[(size_t)row * 1024 + col] = v;
                } else {
                    const int sec = col >> 10;          // 0=q 1=k 2=v
                    const int d = col & 1023;
                    const int h = d >> 6, dk = d & 63;
                    const int b_ = row >> 11, n = row & 2047;
                    const int bh = b_ * 16 + h;
                    if (sec == 0)
                        qo[((size_t)(bh * 2048 + n) << 6) + dk] = bfbits(v * QSCALE);
                    else if (sec == 1)
                        ko[((size_t)(bh * 2048 + n) << 6) + dk] = bfbits(v);
                    else
                        vto[(size_t)(bh * 64 + dk) * 2048 + n] = bfbits(v);
                }
            }
        }
    }
}

// Flash attention. 2 waves/block, each wave owns 32 q-rows (two 16-row groups a/b
// sharing the same staged K/V tile and the same LDS reads). Swapped QK^T keeps P
// in-register (16x16x16 A-fragment layout); log2-domain, deferred per-lane max.
// Q,K: [32][2048][64] bf16 (Q pre-scaled by QSCALE). Vt: [32][64][2048] bf16.
// O: [4096][1024] bf16 (row = b*2048+n, col = h*64+dk).
// Grid (32,32): block covers 64 q-rows of one bh. kv tiles of 64, double-buffered.
// LDS (bytes): K dbuf [0,16K), V dbuf [16K,32K). 32KB -> 4 blocks/CU.
__global__ __launch_bounds__(128, 2) void attn_flash(
    const unsigned short* __restrict__ Q,
    const unsigned short* __restrict__ K,
    const unsigned short* __restrict__ Vt,
    unsigned short* __restrict__ O) {
    __shared__ __attribute__((aligned(128))) unsigned char smem[32768];
    const int lane = threadIdx.x & 63;
    const int w = threadIdx.x >> 6;          // 0..1
    const int g = lane >> 4, c = lane & 15;
    const int c7 = c & 7;
    const int bh = blockIdx.y;
    const int q0 = blockIdx.x * 64 + w * 32; // wave's 32 q-rows
    const unsigned short* Qb = Q + (size_t)bh * 2048 * 64;
    const unsigned short* Kb = K + (size_t)bh * 2048 * 64;
    const unsigned short* Vb = Vt + (size_t)bh * 64 * 2048;

    const int rloc = lane >> 3;
    const int csrc = ((lane & 7) ^ (rloc & 7)) * 8;

    const int chunkKV0 = ((0 + g) ^ c7) * 16;
    const int chunkKV1 = ((4 + g) ^ c7) * 16;
    const int ghalf = (g >> 1);
    const int gsub = (g & 1) * 8;

    bf16x8 aq[2][2];                          // [group][ks]
    #pragma unroll
    for (int qg = 0; qg < 2; ++qg)
        #pragma unroll
        for (int ks = 0; ks < 2; ++ks)
            aq[qg][ks] = *(const bf16x8*)(Qb + (size_t)(q0 + qg * 16 + c) * 64 + ks * 32 + 8 * g);

    f32x4 oa[4] = {}, ob[4] = {};
    f32x4 la = {}, lb = {};
    float ma = -1e30f, mb = -1e30f;           // running max for q-rows (a: q0+c, b: q0+16+c)

    bf16x4 ones4;
    #pragma unroll
    for (int i = 0; i < 4; ++i) ones4[i] = (__bf16)1.0f;

    // prologue: stage tile 0 (wave w does instrs 4w..4w+3 for K and V)
    #pragma unroll
    for (int tt = 0; tt < 4; ++tt) {
        const int t = 4 * w + tt;
        const int row = 8 * t + rloc;
        gl_lds16(Kb + (size_t)row * 64 + csrc, smem + t * 1024);
        gl_lds16(Vb + (size_t)row * 2048 + csrc, smem + 16384 + t * 1024);
    }
    __syncthreads();

    int cur = 0;
    for (int kv = 0; kv < 2048; kv += 64) {
        if (kv + 64 < 2048) {
            const int nb = cur ^ 1;
            #pragma unroll
            for (int tt = 0; tt < 4; ++tt) {
                const int t = 4 * w + tt;
                const int row = 8 * t + rloc;
                gl_lds16(Kb + (size_t)(kv + 64 + row) * 64 + csrc,
                         smem + nb * 8192 + t * 1024);
                gl_lds16(Vb + (size_t)row * 2048 + (kv + 64) + csrc,
                         smem + 16384 + nb * 8192 + t * 1024);
            }
        }

        const unsigned char* Kt = smem + cur * 8192;
        const unsigned char* Vtb = smem + 16384 + cur * 8192;

        // swapped QK^T for both groups; each K b128 read feeds 4 MFMAs
        f32x4 sa[4] = {}, sb[4] = {};
        __builtin_amdgcn_s_setprio(1);
        #pragma unroll
        for (int nj = 0; nj < 4; ++nj) {
            bf16x8 bk0 = *(const bf16x8*)(Kt + nj * 2048 + c * 128 + chunkKV0);
            bf16x8 bk1 = *(const bf16x8*)(Kt + nj * 2048 + c * 128 + chunkKV1);
            sa[nj] = __builtin_amdgcn_mfma_f32_16x16x32_bf16(bk0, aq[0][0], sa[nj], 0, 0, 0);
            sa[nj] = __builtin_amdgcn_mfma_f32_16x16x32_bf16(bk1, aq[0][1], sa[nj], 0, 0, 0);
            sb[nj] = __builtin_amdgcn_mfma_f32_16x16x32_bf16(bk0, aq[1][0], sb[nj], 0, 0, 0);
            sb[nj] = __builtin_amdgcn_mfma_f32_16x16x32_bf16(bk1, aq[1][1], sb[nj], 0, 0, 0);
        }
        __builtin_amdgcn_s_setprio(0);

        // per-lane partial maxes (each lane's 16 values belong to one q-row)
        float pa = sa[0][0], pb = sb[0][0];
        #pragma unroll
        for (int nj = 0; nj < 4; ++nj)
            #pragma unroll
            for (int j = 0; j < 4; ++j) {
                pa = fmaxf(pa, sa[nj][j]);
                pb = fmaxf(pb, sb[nj][j]);
            }

        // deferred max: full reduce + rescale only on growth > 8 (log2 units)
        const bool trig = (pa > ma + 8.f) || (pb > mb + 8.f);
        if (__any((int)trig)) {
            float rm = pa;
            rm = fmaxf(rm, __shfl_xor(rm, 16));
            rm = fmaxf(rm, __shfl_xor(rm, 32));
            float mnew = fmaxf(ma, rm);
            float sc = __builtin_amdgcn_exp2f(ma - mnew);
            ma = mnew;
            #pragma unroll
            for (int j = 0; j < 4; ++j) {
                const float scj = __shfl(sc, 4 * g + j);
                la[j] *= scj;
                #pragma unroll
                for (int ni = 0; ni < 4; ++ni) oa[ni][j] *= scj;
            }
            rm = pb;
            rm = fmaxf(rm, __shfl_xor(rm, 16));
            rm = fmaxf(rm, __shfl_xor(rm, 32));
            mnew = fmaxf(mb, rm);
            sc = __builtin_amdgcn_exp2f(mb - mnew);
            mb = mnew;
            #pragma unroll
            for (int j = 0; j < 4; ++j) {
                const float scj = __shfl(sc, 4 * g + j);
                lb[j] *= scj;
                #pragma unroll
                for (int ni = 0; ni < 4; ++ni) ob[ni][j] *= scj;
            }
        }

        // P = 2^(s - m), packed directly as 16x16x16 A-fragments (k = 4g+j)
        bf16x4 qa_[4], qb_[4];
        #pragma unroll
        for (int nj = 0; nj < 4; ++nj)
            #pragma unroll
            for (int j = 0; j < 4; ++j) {
                qa_[nj][j] = (__bf16)__builtin_amdgcn_exp2f(sa[nj][j] - ma);
                qb_[nj][j] = (__bf16)__builtin_amdgcn_exp2f(sb[nj][j] - mb);
            }

        // PV: each V b64 read feeds both groups; ones-MFMA row sums
        f32x4 lta = {}, ltb = {};
        __builtin_amdgcn_s_setprio(1);
        #pragma unroll
        for (int nj = 0; nj < 4; ++nj) {
            lta = mfma16(qa_[nj], ones4, lta);
            ltb = mfma16(qb_[nj], ones4, ltb);
            #pragma unroll
            for (int ni = 0; ni < 4; ++ni) {
                bf16x4 bv = *(const bf16x4*)(Vtb + (ni * 16 + c) * 128 +
                                             (((2 * nj + ghalf) ^ c7) * 16) + gsub);
                oa[ni] = mfma16(qa_[nj], bv, oa[ni]);
                ob[ni] = mfma16(qb_[nj], bv, ob[ni]);
            }
        }
        __builtin_amdgcn_s_setprio(0);
        la += lta;
        lb += ltb;

        __syncthreads();
        cur ^= 1;
    }

    const int b_ = bh >> 4, h = bh & 15;
    #pragma unroll
    for (int ni = 0; ni < 4; ++ni) {
        #pragma unroll
        for (int j = 0; j < 4; ++j) {
            const int col = h * 64 + ni * 16 + c;
            const int rowa = b_ * 2048 + q0 + 4 * g + j;
            O[(size_t)rowa * 1024 + col] = bfbits(oa[ni][j] / la[j]);
            const int rowb = rowa + 16;
            O[(size_t)rowb * 1024 + col] = bfbits(ob[ni][j] / lb[j]);
        }
    }
}

extern "C" void kernel_launch(void* const* d_in, const int* in_sizes, int n_in,
                              void* d_out, int out_size, void* d_ws, size_t ws_size,
                              hipStream_t stream) {
    const float* x     = (const float*)d_in[0];
    const float* qkv_w = (const float*)d_in[1];
    const float* qkv_b = (const float*)d_in[2];
    const float* out_w = (const float*)d_in[3];
    const float* out_b = (const float*)d_in[4];
    float* out = (float*)d_out;

    char* ws = (char*)d_ws;
    unsigned short* xb   = (unsigned short*)(ws);              //  8 MB (reused as attn-out)
    unsigned short* wqkv = (unsigned short*)(ws + (8u  << 20)); //  6 MB
    unsigned short* wout = (unsigned short*)(ws + (14u << 20)); //  2 MB
    unsigned short* qb   = (unsigned short*)(ws + (16u << 20)); //  8 MB
    unsigned short* kb   = (unsigned short*)(ws + (24u << 20)); //  8 MB
    unsigned short* vtb  = (unsigned short*)(ws + (32u << 20)); //  8 MB  (total 40 MB)

    cvt_all<<<2048, 256, 0, stream>>>((const float4*)x, (const float4*)qkv_w,
                                      (const float4*)out_w, (ushort4*)ws);

    gemm_mfma<0><<<dim3(32, 24), 256, 0, stream>>>(xb, wqkv, qkv_b, qb, kb, vtb, nullptr);

    unsigned short* ao = xb;  // xb no longer needed; reuse for attention output
    attn_flash<<<dim3(32, 32), 128, 0, stream>>>(qb, kb, vtb, ao);

    gemm_mfma<1><<<dim3(32, 8), 256, 0, stream>>>(ao, wout, out_b, nullptr, nullptr, nullptr, out);
}

// Round 9
// 127.628 us; speedup vs baseline: 2.9548x; 1.0222x over previous
//
#include <hip/hip_runtime.h>
#include <hip/hip_bf16.h>

// MultiHeadAttention: x(2,2048,1024) fp32 -> out(2,2048,1024) fp32
// Pipeline: fused cvt->bf16; QKV GEMM (LDS-staged mfma) -> q(*0.125*log2e),k,v^T;
// flash attn (4 waves x 16 q-rows, swapped QK^T, in-reg P, 2-deep pipeline:
// QK(t) issues while softmax+PV(t-1) computes); out GEMM.

typedef __bf16 bf16x8 __attribute__((ext_vector_type(8)));
typedef __bf16 bf16x4 __attribute__((ext_vector_type(4)));
typedef short short4v __attribute__((ext_vector_type(4)));
typedef float f32x4 __attribute__((ext_vector_type(4)));

#define QSCALE 0.18033688011112042f  // 0.125 * log2(e): QK^T lands in log2 domain

__device__ __forceinline__ unsigned short bfbits(float f) {
    union { __bf16 h; unsigned short u; } cv;
    cv.h = (__bf16)f;
    return cv.u;
}

__device__ __forceinline__ f32x4 mfma16(bf16x4 a, bf16x4 b, f32x4 c) {
#if __has_builtin(__builtin_amdgcn_mfma_f32_16x16x16bf16_1k)
    union { bf16x4 h; short4v s; } ua, ub;
    ua.h = a; ub.h = b;
    return __builtin_amdgcn_mfma_f32_16x16x16bf16_1k(ua.s, ub.s, c, 0, 0, 0);
#else
    f32x4 d = c;
    asm volatile("v_mfma_f32_16x16x16_bf16 %0, %1, %2, %0"
                 : "+v"(d) : "v"(a), "v"(b));
    return d;
#endif
}

__device__ __forceinline__ void gl_lds16(const void* g, void* l) {
    __builtin_amdgcn_global_load_lds(
        (__attribute__((address_space(1))) const unsigned int*)g,
        (__attribute__((address_space(3))) unsigned int*)l, 16, 0, 0);
}

// Fused bf16 conversion: x (1048576 f4), qkv_w (786432 f4), out_w (262144 f4)
// into contiguous dst (ws+0: xb 8MB | ws+8M: wqkv 6MB | ws+14M: wout 2MB).
__global__ void cvt_all(const float4* __restrict__ x,
                        const float4* __restrict__ wq,
                        const float4* __restrict__ wo,
                        ushort4* __restrict__ dst) {
    int i = blockIdx.x * blockDim.x + threadIdx.x;
    const int stride = gridDim.x * blockDim.x;
    for (; i < 2097152; i += stride) {
        float4 f;
        if (i < 1048576)       f = x[i];
        else if (i < 1835008)  f = wq[i - 1048576];
        else                   f = wo[i - 1835008];
        ushort4 o;
        o.x = bfbits(f.x); o.y = bfbits(f.y); o.z = bfbits(f.z); o.w = bfbits(f.w);
        dst[i] = o;
    }
}

// C = A(M x 1024) @ W(N x 1024)^T + bias. 128x128 block tile, 4 waves (2x2) of 64x64.
// m97 structure: BK=64 single-buffer LDS, global_load_lds w16 staging, 2-barrier K-loop.
// MODE 0: N=3072, scatter to q (scaled QSCALE), k, vt (v transposed [bh][dk][n]) as bf16.
// MODE 1: N=1024, fp32 out row-major.
template<int MODE>
__global__ __launch_bounds__(256, 3) void gemm_mfma(
    const unsigned short* __restrict__ A,
    const unsigned short* __restrict__ W,
    const float* __restrict__ bias,
    unsigned short* __restrict__ qo,
    unsigned short* __restrict__ ko,
    unsigned short* __restrict__ vto,
    float* __restrict__ fo) {
    __shared__ __attribute__((aligned(128))) unsigned char smem[32768];
    const int lane = threadIdx.x & 63;
    const int w = threadIdx.x >> 6;
    const int g = lane >> 4, c = lane & 15;
    const int wr = w >> 1, wc = w & 1;
    const int row0 = blockIdx.x * 128;
    const int col0 = blockIdx.y * 128;

    const int rloc = lane >> 3;                      // 0..7
    const int csrc = ((lane & 7) ^ rloc) * 8;        // pre-swizzled source chunk (elements)

    f32x4 acc[4][4] = {};

    for (int kt = 0; kt < 1024; kt += 64) {
        #pragma unroll
        for (int i = 0; i < 4; ++i) {
            const int r = i * 32 + w * 8 + rloc;
            gl_lds16(A + (size_t)(row0 + r) * 1024 + kt + csrc,
                     smem + i * 4096 + w * 1024);
            gl_lds16(W + (size_t)(col0 + r) * 1024 + kt + csrc,
                     smem + 16384 + i * 4096 + w * 1024);
        }
        __syncthreads();

        #pragma unroll
        for (int ks = 0; ks < 2; ++ks) {
            bf16x8 a[4], b[4];
            #pragma unroll
            for (int mi = 0; mi < 4; ++mi) {
                const int r = wr * 64 + mi * 16 + c;
                a[mi] = *(const bf16x8*)(smem + r * 128 + (((ks * 4 + g) ^ (r & 7)) * 16));
            }
            #pragma unroll
            for (int ni = 0; ni < 4; ++ni) {
                const int r = wc * 64 + ni * 16 + c;
                b[ni] = *(const bf16x8*)(smem + 16384 + r * 128 + (((ks * 4 + g) ^ (r & 7)) * 16));
            }
            #pragma unroll
            for (int mi = 0; mi < 4; ++mi)
                #pragma unroll
                for (int ni = 0; ni < 4; ++ni)
                    acc[mi][ni] = __builtin_amdgcn_mfma_f32_16x16x32_bf16(
                        a[mi], b[ni], acc[mi][ni], 0, 0, 0);
        }
        __syncthreads();
    }

    #pragma unroll
    for (int mi = 0; mi < 4; ++mi) {
        #pragma unroll
        for (int ni = 0; ni < 4; ++ni) {
            const int col = col0 + wc * 64 + ni * 16 + c;
            const float bv = bias[col];
            #pragma unroll
            for (int j = 0; j < 4; ++j) {
                const int row = row0 + wr * 64 + mi * 16 + 4 * g + j;
                float v = acc[mi][ni][j] + bv;
                if (MODE == 1) {
                    fo[(size_t)row * 1024 + col] = v;
                } else {
                    const int sec = col >> 10;          // 0=q 1=k 2=v
                    const int d = col & 1023;
                    const int h = d >> 6, dk = d & 63;
                    const int b_ = row >> 11, n = row & 2047;
                    const int bh = b_ * 16 + h;
                    if (sec == 0)
                        qo[((size_t)(bh * 2048 + n) << 6) + dk] = bfbits(v * QSCALE);
                    else if (sec == 1)
                        ko[((size_t)(bh * 2048 + n) << 6) + dk] = bfbits(v);
                    else
                        vto[(size_t)(bh * 64 + dk) * 2048 + n] = bfbits(v);
                }
            }
        }
    }
}

// Flash attention, 2-deep pipelined. 4 waves x 16 q-rows; swapped QK^T keeps P
// in-register (16x16x16 A-frag layout). Per iteration: stage(t+1); issue QK(t)
// into one S-set; softmax+PV(t-1) from the other S-set; barrier. QK results are
// consumed a full tile later -> MFMA/LDS latency hidden under softmax VALU.
// Q,K: [32][2048][64] bf16 (Q pre-scaled by QSCALE). Vt: [32][64][2048] bf16.
// O: [4096][1024] bf16. Grid (32,32), 256 threads.
// LDS: K dbuf [0,16K) (2x8KB), V tbuf [16K,40K) (3x8KB). 40KB -> 4 blocks/CU.
__global__ __launch_bounds__(256, 4) void attn_flash(
    const unsigned short* __restrict__ Q,
    const unsigned short* __restrict__ K,
    const unsigned short* __restrict__ Vt,
    unsigned short* __restrict__ O) {
    __shared__ __attribute__((aligned(128))) unsigned char smem[40960];
    const int lane = threadIdx.x & 63;
    const int w = threadIdx.x >> 6;          // 0..3
    const int g = lane >> 4, c = lane & 15;
    const int c7 = c & 7;
    const int bh = blockIdx.y;
    const int q0 = blockIdx.x * 64 + w * 16;
    const unsigned short* Qb = Q + (size_t)bh * 2048 * 64;
    const unsigned short* Kb = K + (size_t)bh * 2048 * 64;
    const unsigned short* Vb = Vt + (size_t)bh * 64 * 2048;

    const int rloc = lane >> 3;
    const int csrc = ((lane & 7) ^ (rloc & 7)) * 8;

    const int chunkKV0 = ((0 + g) ^ c7) * 16;
    const int chunkKV1 = ((4 + g) ^ c7) * 16;
    const int ghalf = (g >> 1);
    const int gsub = (g & 1) * 8;

    bf16x8 aq[2];
    #pragma unroll
    for (int ks = 0; ks < 2; ++ks)
        aq[ks] = *(const bf16x8*)(Qb + (size_t)(q0 + c) * 64 + ks * 32 + 8 * g);

    f32x4 o[4] = {};
    f32x4 l_run = {};
    float m_run = -1e30f;

    bf16x4 ones4;
    #pragma unroll
    for (int i = 0; i < 4; ++i) ones4[i] = (__bf16)1.0f;

    // stage tile u: K(u) -> K buf (u&1), V(u) -> V buf (u%3). 2 instrs/wave each.
    #define STAGE(U, KBUF, VBUF)                                               \
        {                                                                      \
            _Pragma("unroll")                                                  \
            for (int tt = 0; tt < 2; ++tt) {                                   \
                const int t = 2 * w + tt;                                      \
                const int row = 8 * t + rloc;                                  \
                gl_lds16(Kb + (size_t)((U) * 64 + row) * 64 + csrc,            \
                         smem + (KBUF) * 8192 + t * 1024);                     \
                gl_lds16(Vb + (size_t)row * 2048 + (U) * 64 + csrc,            \
                         smem + 16384 + (VBUF) * 8192 + t * 1024);             \
            }                                                                  \
        }

    // swapped QK^T for tile in K buf KBUF -> S (lane holds P[q=c][kv=16nj+4g+j])
    #define QKT(S, KBUF)                                                       \
        {                                                                      \
            const unsigned char* Kt = smem + (KBUF) * 8192;                    \
            __builtin_amdgcn_s_setprio(1);                                     \
            _Pragma("unroll")                                                  \
            for (int nj = 0; nj < 4; ++nj) {                                   \
                bf16x8 bk0 = *(const bf16x8*)(Kt + nj * 2048 + c * 128 + chunkKV0); \
                bf16x8 bk1 = *(const bf16x8*)(Kt + nj * 2048 + c * 128 + chunkKV1); \
                S[nj] = __builtin_amdgcn_mfma_f32_16x16x32_bf16(bk0, aq[0], S[nj], 0, 0, 0); \
                S[nj] = __builtin_amdgcn_mfma_f32_16x16x32_bf16(bk1, aq[1], S[nj], 0, 0, 0); \
            }                                                                  \
            __builtin_amdgcn_s_setprio(0);                                     \
        }

    // softmax + PV for the S-set of the previous tile, V in V buf VBUF
    #define SMPV(S, VBUF)                                                      \
        {                                                                      \
            float pmax = S[0][0];                                              \
            _Pragma("unroll")                                                  \
            for (int nj = 0; nj < 4; ++nj)                                     \
                _Pragma("unroll")                                              \
                for (int j = 0; j < 4; ++j)                                    \
                    pmax = fmaxf(pmax, S[nj][j]);                              \
            if (__any((int)(pmax > m_run + 8.f))) {                            \
                float rm = pmax;                                               \
                rm = fmaxf(rm, __shfl_xor(rm, 16));                            \
                rm = fmaxf(rm, __shfl_xor(rm, 32));                            \
                const float mnew = fmaxf(m_run, rm);                           \
                const float sc = __builtin_amdgcn_exp2f(m_run - mnew);         \
                m_run = mnew;                                                  \
                _Pragma("unroll")                                              \
                for (int j = 0; j < 4; ++j) {                                  \
                    const float scj = __shfl(sc, 4 * g + j);                   \
                    l_run[j] *= scj;                                           \
                    _Pragma("unroll")                                          \
                    for (int ni = 0; ni < 4; ++ni) o[ni][j] *= scj;            \
                }                                                              \
            }                                                                  \
            bf16x4 p[4];                                                       \
            _Pragma("unroll")                                                  \
            for (int nj = 0; nj < 4; ++nj)                                     \
                _Pragma("unroll")                                              \
                for (int j = 0; j < 4; ++j)                                    \
                    p[nj][j] = (__bf16)__builtin_amdgcn_exp2f(S[nj][j] - m_run); \
            const unsigned char* Vtb = smem + 16384 + (VBUF) * 8192;           \
            f32x4 lt = {};                                                     \
            __builtin_amdgcn_s_setprio(1);                                     \
            _Pragma("unroll")                                                  \
            for (int nj = 0; nj < 4; ++nj) {                                   \
                lt = mfma16(p[nj], ones4, lt);                                 \
                _Pragma("unroll")                                              \
                for (int ni = 0; ni < 4; ++ni) {                               \
                    bf16x4 bv = *(const bf16x4*)(Vtb + (ni * 16 + c) * 128 +   \
                                 (((2 * nj + ghalf) ^ c7) * 16) + gsub);       \
                    o[ni] = mfma16(p[nj], bv, o[ni]);                          \
                }                                                              \
            }                                                                  \
            __builtin_amdgcn_s_setprio(0);                                     \
            l_run += lt;                                                       \
        }

    f32x4 sA[4] = {}, sB[4] = {};

    // prologue: stage(0); sync; { stage(1); QK(0)->sA; } sync
    STAGE(0, 0, 0);
    __syncthreads();
    STAGE(1, 1, 1);
    QKT(sA, 0);
    __syncthreads();

    // pairs (u, u+1) for u = 1,3,...,29: QK tiles 1..30, PV tiles 0..29
    for (int u = 1; u < 31; u += 2) {
        // tile u (odd): stage(u+1) -> K buf0, V buf (u+1)%3 ; QK(u)->sB ; PV(sA, V(u-1))
        STAGE(u + 1, 0, (u + 1) % 3);
        QKT(sB, 1);
        SMPV(sA, (u - 1) % 3);
        __syncthreads();
        // clear sA for reuse as next QK accumulator
        #pragma unroll
        for (int nj = 0; nj < 4; ++nj) sA[nj] = f32x4{};
        // tile u+1 (even): stage(u+2) -> K buf1, V buf (u+2)%3 ; QK(u+1)->sA ; PV(sB, V(u))
        STAGE(u + 2, 1, (u + 2) % 3);
        QKT(sA, 0);
        SMPV(sB, u % 3);
        __syncthreads();
        #pragma unroll
        for (int nj = 0; nj < 4; ++nj) sB[nj] = f32x4{};
    }
    // tail: tile 31: QK(31)->sB (K buf 1, staged at u=29 bodyB); PV(sA = tile30, V buf 0)
    QKT(sB, 1);
    SMPV(sA, 0);
    // final: PV(sB = tile31, V buf 31%3 = 1)
    SMPV(sB, 1);

    #undef STAGE
    #undef QKT
    #undef SMPV

    const int b_ = bh >> 4, h = bh & 15;
    #pragma unroll
    for (int ni = 0; ni < 4; ++ni) {
        #pragma unroll
        for (int j = 0; j < 4; ++j) {
            const int row = b_ * 2048 + q0 + 4 * g + j;
            const int col = h * 64 + ni * 16 + c;
            O[(size_t)row * 1024 + col] = bfbits(o[ni][j] / l_run[j]);
        }
    }
}

extern "C" void kernel_launch(void* const* d_in, const int* in_sizes, int n_in,
                              void* d_out, int out_size, void* d_ws, size_t ws_size,
                              hipStream_t stream) {
    const float* x     = (const float*)d_in[0];
    const float* qkv_w = (const float*)d_in[1];
    const float* qkv_b = (const float*)d_in[2];
    const float* out_w = (const float*)d_in[3];
    const float* out_b = (const float*)d_in[4];
    float* out = (float*)d_out;

    char* ws = (char*)d_ws;
    unsigned short* xb   = (unsigned short*)(ws);              //  8 MB (reused as attn-out)
    unsigned short* wqkv = (unsigned short*)(ws + (8u  << 20)); //  6 MB
    unsigned short* wout = (unsigned short*)(ws + (14u << 20)); //  2 MB
    unsigned short* qb   = (unsigned short*)(ws + (16u << 20)); //  8 MB
    unsigned short* kb   = (unsigned short*)(ws + (24u << 20)); //  8 MB
    unsigned short* vtb  = (unsigned short*)(ws + (32u << 20)); //  8 MB  (total 40 MB)

    cvt_all<<<2048, 256, 0, stream>>>((const float4*)x, (const float4*)qkv_w,
                                      (const float4*)out_w, (ushort4*)ws);

    gemm_mfma<0><<<dim3(32, 24), 256, 0, stream>>>(xb, wqkv, qkv_b, qb, kb, vtb, nullptr);

    unsigned short* ao = xb;  // xb no longer needed; reuse for attention output
    attn_flash<<<dim3(32, 32), 256, 0, stream>>>(qb, kb, vtb, ao);

    gemm_mfma<1><<<dim3(32, 8), 256, 0, stream>>>(ao, wout, out_b, nullptr, nullptr, nullptr, out);
}

// Round 10
// 126.089 us; speedup vs baseline: 2.9909x; 1.0122x over previous
//
#include <hip/hip_runtime.h>
#include <hip/hip_bf16.h>

// MultiHeadAttention: x(2,2048,1024) fp32 -> out(2,2048,1024) fp32
// Pipeline: fused cvt->bf16; QKV GEMM (LDS-staged mfma) -> q(*0.125*log2e),k,v^T;
// flash attn (8 waves x 16 q-rows sharing one K/V dbuf, swapped QK^T, in-reg P,
// deferred max, 2-bit-row XOR swizzle); out GEMM.

typedef __bf16 bf16x8 __attribute__((ext_vector_type(8)));
typedef __bf16 bf16x4 __attribute__((ext_vector_type(4)));
typedef short short4v __attribute__((ext_vector_type(4)));
typedef float f32x4 __attribute__((ext_vector_type(4)));

#define QSCALE 0.18033688011112042f  // 0.125 * log2(e): QK^T lands in log2 domain

__device__ __forceinline__ unsigned short bfbits(float f) {
    union { __bf16 h; unsigned short u; } cv;
    cv.h = (__bf16)f;
    return cv.u;
}

__device__ __forceinline__ f32x4 mfma16(bf16x4 a, bf16x4 b, f32x4 c) {
#if __has_builtin(__builtin_amdgcn_mfma_f32_16x16x16bf16_1k)
    union { bf16x4 h; short4v s; } ua, ub;
    ua.h = a; ub.h = b;
    return __builtin_amdgcn_mfma_f32_16x16x16bf16_1k(ua.s, ub.s, c, 0, 0, 0);
#else
    f32x4 d = c;
    asm volatile("v_mfma_f32_16x16x16_bf16 %0, %1, %2, %0"
                 : "+v"(d) : "v"(a), "v"(b));
    return d;
#endif
}

__device__ __forceinline__ void gl_lds16(const void* g, void* l) {
    __builtin_amdgcn_global_load_lds(
        (__attribute__((address_space(1))) const unsigned int*)g,
        (__attribute__((address_space(3))) unsigned int*)l, 16, 0, 0);
}

// Fused bf16 conversion: x (1048576 f4), qkv_w (786432 f4), out_w (262144 f4)
// into contiguous dst (ws+0: xb 8MB | ws+8M: wqkv 6MB | ws+14M: wout 2MB).
__global__ void cvt_all(const float4* __restrict__ x,
                        const float4* __restrict__ wq,
                        const float4* __restrict__ wo,
                        ushort4* __restrict__ dst) {
    int i = blockIdx.x * blockDim.x + threadIdx.x;
    const int stride = gridDim.x * blockDim.x;
    for (; i < 2097152; i += stride) {
        float4 f;
        if (i < 1048576)       f = x[i];
        else if (i < 1835008)  f = wq[i - 1048576];
        else                   f = wo[i - 1835008];
        ushort4 o;
        o.x = bfbits(f.x); o.y = bfbits(f.y); o.z = bfbits(f.z); o.w = bfbits(f.w);
        dst[i] = o;
    }
}

// C = A(M x 1024) @ W(N x 1024)^T + bias. 128x128 block tile, 4 waves (2x2) of 64x64.
// m97 structure: BK=64 single-buffer LDS, global_load_lds w16 staging, 2-barrier K-loop.
// MODE 0: N=3072, scatter to q (scaled QSCALE), k, vt (v transposed [bh][dk][n]) as bf16.
// MODE 1: N=1024, fp32 out row-major.
template<int MODE>
__global__ __launch_bounds__(256, 3) void gemm_mfma(
    const unsigned short* __restrict__ A,
    const unsigned short* __restrict__ W,
    const float* __restrict__ bias,
    unsigned short* __restrict__ qo,
    unsigned short* __restrict__ ko,
    unsigned short* __restrict__ vto,
    float* __restrict__ fo) {
    __shared__ __attribute__((aligned(128))) unsigned char smem[32768];
    const int lane = threadIdx.x & 63;
    const int w = threadIdx.x >> 6;
    const int g = lane >> 4, c = lane & 15;
    const int wr = w >> 1, wc = w & 1;
    const int row0 = blockIdx.x * 128;
    const int col0 = blockIdx.y * 128;

    const int rloc = lane >> 3;                      // 0..7
    const int csrc = ((lane & 7) ^ rloc) * 8;        // pre-swizzled source chunk (elements)

    f32x4 acc[4][4] = {};

    for (int kt = 0; kt < 1024; kt += 64) {
        #pragma unroll
        for (int i = 0; i < 4; ++i) {
            const int r = i * 32 + w * 8 + rloc;
            gl_lds16(A + (size_t)(row0 + r) * 1024 + kt + csrc,
                     smem + i * 4096 + w * 1024);
            gl_lds16(W + (size_t)(col0 + r) * 1024 + kt + csrc,
                     smem + 16384 + i * 4096 + w * 1024);
        }
        __syncthreads();

        #pragma unroll
        for (int ks = 0; ks < 2; ++ks) {
            bf16x8 a[4], b[4];
            #pragma unroll
            for (int mi = 0; mi < 4; ++mi) {
                const int r = wr * 64 + mi * 16 + c;
                a[mi] = *(const bf16x8*)(smem + r * 128 + (((ks * 4 + g) ^ (r & 7)) * 16));
            }
            #pragma unroll
            for (int ni = 0; ni < 4; ++ni) {
                const int r = wc * 64 + ni * 16 + c;
                b[ni] = *(const bf16x8*)(smem + 16384 + r * 128 + (((ks * 4 + g) ^ (r & 7)) * 16));
            }
            #pragma unroll
            for (int mi = 0; mi < 4; ++mi)
                #pragma unroll
                for (int ni = 0; ni < 4; ++ni)
                    acc[mi][ni] = __builtin_amdgcn_mfma_f32_16x16x32_bf16(
                        a[mi], b[ni], acc[mi][ni], 0, 0, 0);
        }
        __syncthreads();
    }

    #pragma unroll
    for (int mi = 0; mi < 4; ++mi) {
        #pragma unroll
        for (int ni = 0; ni < 4; ++ni) {
            const int col = col0 + wc * 64 + ni * 16 + c;
            const float bv = bias[col];
            #pragma unroll
            for (int j = 0; j < 4; ++j) {
                const int row = row0 + wr * 64 + mi * 16 + 4 * g + j;
                float v = acc[mi][ni][j] + bv;
                if (MODE == 1) {
                    fo[(size_t)row * 1024 + col] = v;
                } else {
                    const int sec = col >> 10;          // 0=q 1=k 2=v
                    const int d = col & 1023;
                    const int h = d >> 6, dk = d & 63;
                    const int b_ = row >> 11, n = row & 2047;
                    const int bh = b_ * 16 + h;
                    if (sec == 0)
                        qo[((size_t)(bh * 2048 + n) << 6) + dk] = bfbits(v * QSCALE);
                    else if (sec == 1)
                        ko[((size_t)(bh * 2048 + n) << 6) + dk] = bfbits(v);
                    else
                        vto[(size_t)(bh * 64 + dk) * 2048 + n] = bfbits(v);
                }
            }
        }
    }
}

// Flash attention. 8 waves x 16 q-rows = 128 q-rows/block, all sharing one 32KB
// K/V double-buffer (4 blocks/CU -> 32 waves/CU). Swapped QK^T keeps P in-register
// (16x16x16 A-frag layout); log2-domain softmax with deferred per-lane max.
// LDS swizzle: 16B chunk position = data_chunk ^ (row&7) ^ (((row>>3)&1)<<2)
// (second term kills the c vs c+8 same-bank aliasing); involution applied on the
// staging SOURCE address and the read side identically.
// Q,K: [32][2048][64] bf16 (Q pre-scaled by QSCALE). Vt: [32][64][2048] bf16.
// O: [4096][1024] bf16 (row = b*2048+n, col = h*64+dk).
// Grid (16,32), 512 threads. kv tiles of 64, double-buffered.
// LDS (bytes): K dbuf [0,16K), V dbuf [16K,32K).
__global__ __launch_bounds__(512, 8) void attn_flash(
    const unsigned short* __restrict__ Q,
    const unsigned short* __restrict__ K,
    const unsigned short* __restrict__ Vt,
    unsigned short* __restrict__ O) {
    __shared__ __attribute__((aligned(128))) unsigned char smem[32768];
    const int lane = threadIdx.x & 63;
    const int w = threadIdx.x >> 6;          // 0..7
    const int g = lane >> 4, c = lane & 15;
    const int c7 = c & 7;
    const int swz = c7 ^ (((c >> 3) & 1) << 2);
    const int bh = blockIdx.y;
    const int q0 = blockIdx.x * 128 + w * 16;
    const unsigned short* Qb = Q + (size_t)bh * 2048 * 64;
    const unsigned short* Kb = K + (size_t)bh * 2048 * 64;
    const unsigned short* Vb = Vt + (size_t)bh * 64 * 2048;

    // staging: wave w writes rows 8w..8w+7 (1KB) of each tile; source pre-swizzled
    const int rloc = lane >> 3;
    const int csrc = ((lane & 7) ^ rloc ^ ((w & 1) << 2)) * 8;

    const int chunkKV0 = ((0 + g) ^ swz) * 16;
    const int chunkKV1 = ((4 + g) ^ swz) * 16;
    const int ghalf = g >> 1;
    const int gsub = (g & 1) * 8;

    bf16x8 aq[2];
    #pragma unroll
    for (int ks = 0; ks < 2; ++ks)
        aq[ks] = *(const bf16x8*)(Qb + (size_t)(q0 + c) * 64 + ks * 32 + 8 * g);

    f32x4 o[4] = {};
    f32x4 l_run = {};
    float m_run = -1e30f;

    bf16x4 ones4;
    #pragma unroll
    for (int i = 0; i < 4; ++i) ones4[i] = (__bf16)1.0f;

    // prologue: stage tile 0 into buffer 0 (1 K-instr + 1 V-instr per wave)
    {
        const int row = 8 * w + rloc;
        gl_lds16(Kb + (size_t)row * 64 + csrc, smem + w * 1024);
        gl_lds16(Vb + (size_t)row * 2048 + csrc, smem + 16384 + w * 1024);
    }
    __syncthreads();

    for (int t = 0; t < 32; ++t) {
        const int cur = t & 1;
        if (t + 1 < 32) {
            const int nb = cur ^ 1;
            const int row = 8 * w + rloc;
            gl_lds16(Kb + (size_t)((t + 1) * 64 + row) * 64 + csrc,
                     smem + nb * 8192 + w * 1024);
            gl_lds16(Vb + (size_t)row * 2048 + (t + 1) * 64 + csrc,
                     smem + 16384 + nb * 8192 + w * 1024);
        }

        const unsigned char* Kt = smem + cur * 8192;
        const unsigned char* Vtb = smem + 16384 + cur * 8192;

        // swapped QK^T: s[nj] = mfma(A=K, B=Q) -> lane holds P[q=c][kv=16nj+4g+j]
        f32x4 s[4] = {};
        __builtin_amdgcn_s_setprio(1);
        #pragma unroll
        for (int nj = 0; nj < 4; ++nj) {
            bf16x8 bk0 = *(const bf16x8*)(Kt + nj * 2048 + c * 128 + chunkKV0);
            bf16x8 bk1 = *(const bf16x8*)(Kt + nj * 2048 + c * 128 + chunkKV1);
            s[nj] = __builtin_amdgcn_mfma_f32_16x16x32_bf16(bk0, aq[0], s[nj], 0, 0, 0);
            s[nj] = __builtin_amdgcn_mfma_f32_16x16x32_bf16(bk1, aq[1], s[nj], 0, 0, 0);
        }
        __builtin_amdgcn_s_setprio(0);

        // per-lane partial max (all 16 values belong to q-row c)
        float pmax = s[0][0];
        #pragma unroll
        for (int nj = 0; nj < 4; ++nj)
            #pragma unroll
            for (int j = 0; j < 4; ++j)
                pmax = fmaxf(pmax, s[nj][j]);

        // deferred max: full reduce + rescale only on growth > 8 (log2 units)
        if (__any((int)(pmax > m_run + 8.f))) {
            float rm = pmax;
            rm = fmaxf(rm, __shfl_xor(rm, 16));
            rm = fmaxf(rm, __shfl_xor(rm, 32));
            const float mnew = fmaxf(m_run, rm);
            const float sc = __builtin_amdgcn_exp2f(m_run - mnew);
            m_run = mnew;
            #pragma unroll
            for (int j = 0; j < 4; ++j) {
                const float scj = __shfl(sc, 4 * g + j);
                l_run[j] *= scj;
                #pragma unroll
                for (int ni = 0; ni < 4; ++ni) o[ni][j] *= scj;
            }
        }

        // P = 2^(s - m), packed directly as 16x16x16 A-fragments (k = 4g+j)
        bf16x4 p[4];
        #pragma unroll
        for (int nj = 0; nj < 4; ++nj)
            #pragma unroll
            for (int j = 0; j < 4; ++j)
                p[nj][j] = (__bf16)__builtin_amdgcn_exp2f(s[nj][j] - m_run);

        // PV via K=16 MFMAs (B = V^T b64 frags) + ones-MFMA row sums
        f32x4 lt = {};
        __builtin_amdgcn_s_setprio(1);
        #pragma unroll
        for (int nj = 0; nj < 4; ++nj) {
            lt = mfma16(p[nj], ones4, lt);
            #pragma unroll
            for (int ni = 0; ni < 4; ++ni) {
                bf16x4 bv = *(const bf16x4*)(Vtb + (ni * 16 + c) * 128 +
                                             (((2 * nj + ghalf) ^ swz) * 16) + gsub);
                o[ni] = mfma16(p[nj], bv, o[ni]);
            }
        }
        __builtin_amdgcn_s_setprio(0);
        l_run += lt;

        __syncthreads();
    }

    const int b_ = bh >> 4, h = bh & 15;
    #pragma unroll
    for (int ni = 0; ni < 4; ++ni) {
        #pragma unroll
        for (int j = 0; j < 4; ++j) {
            const int row = b_ * 2048 + q0 + 4 * g + j;
            const int col = h * 64 + ni * 16 + c;
            O[(size_t)row * 1024 + col] = bfbits(o[ni][j] / l_run[j]);
        }
    }
}

extern "C" void kernel_launch(void* const* d_in, const int* in_sizes, int n_in,
                              void* d_out, int out_size, void* d_ws, size_t ws_size,
                              hipStream_t stream) {
    const float* x     = (const float*)d_in[0];
    const float* qkv_w = (const float*)d_in[1];
    const float* qkv_b = (const float*)d_in[2];
    const float* out_w = (const float*)d_in[3];
    const float* out_b = (const float*)d_in[4];
    float* out = (float*)d_out;

    char* ws = (char*)d_ws;
    unsigned short* xb   = (unsigned short*)(ws);              //  8 MB (reused as attn-out)
    unsigned short* wqkv = (unsigned short*)(ws + (8u  << 20)); //  6 MB
    unsigned short* wout = (unsigned short*)(ws + (14u << 20)); //  2 MB
    unsigned short* qb   = (unsigned short*)(ws + (16u << 20)); //  8 MB
    unsigned short* kb   = (unsigned short*)(ws + (24u << 20)); //  8 MB
    unsigned short* vtb  = (unsigned short*)(ws + (32u << 20)); //  8 MB  (total 40 MB)

    cvt_all<<<2048, 256, 0, stream>>>((const float4*)x, (const float4*)qkv_w,
                                      (const float4*)out_w, (ushort4*)ws);

    gemm_mfma<0><<<dim3(32, 24), 256, 0, stream>>>(xb, wqkv, qkv_b, qb, kb, vtb, nullptr);

    unsigned short* ao = xb;  // xb no longer needed; reuse for attention output
    attn_flash<<<dim3(16, 32), 512, 0, stream>>>(qb, kb, vtb, ao);

    gemm_mfma<1><<<dim3(32, 8), 256, 0, stream>>>(ao, wout, out_b, nullptr, nullptr, nullptr, out);
}